// Round 3
// baseline (1084.344 us; speedup 1.0000x reference)
//
#include <hip/hip_runtime.h>
#include <math.h>

// Problem constants (match reference file)
#define F_IN   512
#define F_HID  256
#define N_CLS  41

#define CHUNK  16384         // edges per workgroup in hist/scatter passes
#define MAXBK  3200          // LDS capacity for bucket arrays (NBK = ceil(M/32) = 3125)
#define PKMASK 0x1FFFF       // low 17 bits = src (M < 131072)
#define STILE_SH 12          // src locality tile = 4096 nodes
#define NKEY   1024          // 32 local-dst * 32 src-tiles

typedef __attribute__((ext_vector_type(8))) short     bf16x8;   // MFMA A/B frag
typedef __attribute__((ext_vector_type(8))) unsigned short u16x8;
typedef __attribute__((ext_vector_type(4))) float     f32x4;    // MFMA C/D frag

__device__ __forceinline__ float b2f(unsigned short u) {
    union { unsigned int i; float f; } v; v.i = ((unsigned int)u) << 16; return v.f;
}
__device__ __forceinline__ unsigned short f2b(float f) {  // RTN-even f32->bf16
    unsigned int u = __float_as_uint(f);
    u = (u + 0x7fffu + ((u >> 16) & 1u)) >> 16;
    return (unsigned short)u;
}

// ================= CSR build, atomic-storm-free =================
// Pass 1: per-WG LDS histogram over dst buckets (bucket = 32 nodes).
__global__ __launch_bounds__(256) void hist_pass(const int* __restrict__ edst,
                                                 int* __restrict__ hist_g,
                                                 int E, int NBK, int NW) {
    __shared__ int lh[MAXBK];
    int t = threadIdx.x, w = blockIdx.x;
    for (int b = t; b < NBK; b += 256) lh[b] = 0;
    __syncthreads();
    int e0 = w * CHUNK;
#pragma unroll 4
    for (int i = 0; i < CHUNK / 256; i++) {
        int e = e0 + i * 256 + t;
        if (e < E) atomicAdd(&lh[edst[e] >> 5], 1);
    }
    __syncthreads();
    for (int b = t; b < NBK; b += 256) hist_g[(size_t)b * NW + w] = lh[b];
}

// Pass 2a: bucket totals.
__global__ __launch_bounds__(256) void s1_btot(const int* __restrict__ hist_g,
                                               int* __restrict__ btot,
                                               int NBK, int NW) {
    int b = blockIdx.x * 256 + threadIdx.x;
    if (b >= NBK) return;
    const int* row = &hist_g[(size_t)b * NW];
    int s = 0;
    for (int w = 0; w < NW; w++) s += row[w];
    btot[b] = s;
}

// Pass 2b: exclusive scan of bucket totals -> bbase[0..NBK], bbase[NBK]=E.
__global__ __launch_bounds__(256) void s2_scan(const int* __restrict__ btot,
                                               int* __restrict__ bbase, int NBK) {
    __shared__ int ls[MAXBK];
    __shared__ int ss[257];
    int t = threadIdx.x;
    const int CH = (MAXBK + 255) / 256;  // 13
    for (int b = t; b < NBK; b += 256) ls[b] = btot[b];
    __syncthreads();
    int s = 0;
    for (int i = 0; i < CH; i++) {
        int idx = t * CH + i;
        if (idx < NBK) s += ls[idx];
    }
    ss[t] = s;
    __syncthreads();
    if (t == 0) {
        int run = 0;
        for (int i = 0; i < 256; i++) { int v = ss[i]; ss[i] = run; run += v; }
        ss[256] = run;
    }
    __syncthreads();
    int run = ss[t];
    for (int i = 0; i < CH; i++) {
        int idx = t * CH + i;
        if (idx < NBK) { int v = ls[idx]; ls[idx] = run; run += v; }
    }
    __syncthreads();
    for (int b = t; b < NBK; b += 256) bbase[b] = ls[b];
    if (t == 0) bbase[NBK] = ss[256];
}

// Pass 2c: per-bucket row exclusive scan -> per-WG write bases.
__global__ __launch_bounds__(256) void s3_rowscan(int* __restrict__ hist_g,
                                                  const int* __restrict__ bbase,
                                                  int NBK, int NW) {
    int b = blockIdx.x * 256 + threadIdx.x;
    if (b >= NBK) return;
    int* row = &hist_g[(size_t)b * NW];
    int run = bbase[b];
    for (int w = 0; w < NW; w++) { int v = row[w]; row[w] = run; run += v; }
}

// Pass 3: scatter edges into WG-private per-bucket ranges (no global atomics).
__global__ __launch_bounds__(256) void scatter_pass(const int* __restrict__ esrc,
                                                    const int* __restrict__ edst,
                                                    const int* __restrict__ hist_g,
                                                    int* __restrict__ packed,
                                                    int E, int NBK, int NW) {
    __shared__ int cur[MAXBK];
    int t = threadIdx.x, w = blockIdx.x;
    for (int b = t; b < NBK; b += 256) cur[b] = hist_g[(size_t)b * NW + w];
    __syncthreads();
    int e0 = w * CHUNK;
#pragma unroll 4
    for (int i = 0; i < CHUNK / 256; i++) {
        int e = e0 + i * 256 + t;
        if (e < E) {
            int d = edst[e];
            int pos = atomicAdd(&cur[d >> 5], 1);
            packed[pos] = esrc[e] | ((d & 31) << 17);
        }
    }
}

// Pass 4: per-bucket counting sort by (local dst, src tile) -> dst-sorted CSR
// (packed2), per-node row pointers rp (inclusive end), and dinv.
__global__ __launch_bounds__(256) void bucket_sort(const int* __restrict__ packed,
                                                   const int* __restrict__ bbase,
                                                   int* __restrict__ packed2,
                                                   int* __restrict__ rp,
                                                   float* __restrict__ dinv, int M) {
    __shared__ int cnt[NKEY];
    __shared__ int ss[256];
    __shared__ int rtot[32];
    int b = blockIdx.x, t = threadIdx.x;
    int start = bbase[b], end = bbase[b + 1];
    for (int i = t; i < NKEY; i += 256) cnt[i] = 0;
    __syncthreads();
    for (int e = start + t; e < end; e += 256) {
        int p = packed[e];
        atomicAdd(&cnt[(((p >> 17) & 31) << 5) | ((p & PKMASK) >> STILE_SH)], 1);
    }
    __syncthreads();
    // per-node totals -> rtot (for rp) and dinv
    if (t < 32) {
        int s = 0;
#pragma unroll
        for (int i = 0; i < 32; i++) s += cnt[(t << 5) + i];
        rtot[t] = s;
        int node = (b << 5) + t;
        if (node < M) dinv[node] = rsqrtf((float)s + 1.0f);
    }
    int i0 = t << 2;  // each thread owns 4 consecutive counters for the scan
    int v0 = cnt[i0], v1 = cnt[i0 + 1], v2 = cnt[i0 + 2], v3 = cnt[i0 + 3];
    ss[t] = v0 + v1 + v2 + v3;
    __syncthreads();
    if (t == 0) {
        int run = start;
#pragma unroll
        for (int i = 0; i < 32; i++) {
            run += rtot[i];
            int node = (b << 5) + i;
            if (node < M) rp[node] = run;  // inclusive end of row
        }
        run = start;
        for (int i = 0; i < 256; i++) { int v = ss[i]; ss[i] = run; run += v; }
    }
    __syncthreads();
    int run = ss[t];
    cnt[i0] = run; run += v0;
    cnt[i0 + 1] = run; run += v1;
    cnt[i0 + 2] = run; run += v2;
    cnt[i0 + 3] = run;
    __syncthreads();
    for (int e = start + t; e < end; e += 256) {
        int p = packed[e];
        int pos = atomicAdd(&cnt[(((p >> 17) & 31) << 5) | ((p & PKMASK) >> STILE_SH)], 1);
        packed2[pos] = p;
    }
}

// ========== weight prep: W1t[n][k]=bf16(W1[k][n]); W2t[n][k]=bf16(W2[k][n]) =====

__global__ __launch_bounds__(256) void cvt_W1t(const float* __restrict__ W1,
                                               unsigned short* __restrict__ W1t) {
    int n = blockIdx.x;  // 0..255
    for (int k = threadIdx.x; k < F_IN; k += 256)
        W1t[n * F_IN + k] = f2b(W1[(size_t)k * F_HID + n]);
}

__global__ __launch_bounds__(256) void cvt_W2t(const float* __restrict__ W2,
                                               unsigned short* __restrict__ W2t) {
    int n = blockIdx.x;   // 0..47 (padded)
    int k = threadIdx.x;  // 0..255
    W2t[n * F_HID + k] = (n < N_CLS) ? f2b(W2[(size_t)k * N_CLS + n])
                                     : (unsigned short)0;
}

// ====== MFMA GEMM1: h1s = dinv[m] * (bf16(x) @ bf16(W1))  (M x 512)@(512 x 256) ==
// 128x256 tile (full N in one block), BK=32, 512 threads = 8 waves (2x4 of 64x64).
// x read ONCE. Output pre-scaled by dinv[row], bf16, written FEATURE-BLOCK-MAJOR:
// H1 layout [4][M][64] so csr_agg1's per-pass gather footprint is 12.8 MB.

__global__ __launch_bounds__(512) void mfma_gemm1(const float* __restrict__ A,
                                                  const unsigned short* __restrict__ Bt,
                                                  const float* __restrict__ dinv,
                                                  unsigned short* __restrict__ H1,
                                                  int M) {
    __shared__ unsigned short As[128 * 40];  // [m][k], row 40 shorts (pad)
    __shared__ unsigned short Bs[256 * 40];  // [n][k]
    int tid = threadIdx.x;
    int wave = tid >> 6, lane = tid & 63;
    int quad = lane >> 4, l15 = lane & 15;
    int m0 = blockIdx.x * 128;
    int wm = (wave & 1) * 64, wn = (wave >> 1) * 64;

    f32x4 acc[4][4] = {};

    int ar = tid >> 2, aq = tid & 3;   // A: row 0..127, 8-float quarter
    int bn = tid >> 1, bc = tid & 1;   // B: row(n) 0..255, chunk parity

    for (int k0 = 0; k0 < F_IN; k0 += 32) {
        // ---- stage A (f32 -> bf16) ----
        {
            int gm = m0 + ar;
            float4 v0, v1;
            if (gm < M) {
                const float4* ap = (const float4*)&A[(size_t)gm * F_IN + k0 + aq * 8];
                v0 = ap[0]; v1 = ap[1];
            } else {
                v0 = v1 = make_float4(0.f, 0.f, 0.f, 0.f);
            }
            u16x8 w;
            w[0]=f2b(v0.x); w[1]=f2b(v0.y); w[2]=f2b(v0.z); w[3]=f2b(v0.w);
            w[4]=f2b(v1.x); w[5]=f2b(v1.y); w[6]=f2b(v1.z); w[7]=f2b(v1.w);
            *(u16x8*)&As[ar * 40 + aq * 8] = w;
        }
        // ---- stage B (already bf16) ----
        {
            const unsigned short* bp = &Bt[(size_t)bn * F_IN + k0];
            *(u16x8*)&Bs[bn * 40 + bc * 8]       = *(const u16x8*)(bp + bc * 8);
            *(u16x8*)&Bs[bn * 40 + (bc + 2) * 8] = *(const u16x8*)(bp + bc * 8 + 16);
        }
        __syncthreads();
        bf16x8 af[4], bfr[4];
#pragma unroll
        for (int i = 0; i < 4; i++)
            af[i] = *(const bf16x8*)&As[(wm + i * 16 + l15) * 40 + quad * 8];
#pragma unroll
        for (int j = 0; j < 4; j++)
            bfr[j] = *(const bf16x8*)&Bs[(wn + j * 16 + l15) * 40 + quad * 8];
#pragma unroll
        for (int i = 0; i < 4; i++)
#pragma unroll
            for (int j = 0; j < 4; j++)
                acc[i][j] = __builtin_amdgcn_mfma_f32_16x16x32_bf16(
                    af[i], bfr[j], acc[i][j], 0, 0, 0);
        __syncthreads();
    }
    // ---- epilogue: C layout col=l15, row=quad*4+rr; pre-scale by dinv[row];
    //      write into [feat_block][node][64] layout ----
#pragma unroll
    for (int i = 0; i < 4; i++) {
#pragma unroll
        for (int rr = 0; rr < 4; rr++) {
            int gm = m0 + wm + i * 16 + quad * 4 + rr;
            if (gm < M) {
                float dv = dinv[gm];
#pragma unroll
                for (int j = 0; j < 4; j++) {
                    int gn = wn + j * 16 + l15;
                    H1[((size_t)(gn >> 6) * M + gm) * 64 + (gn & 63)] =
                        f2b(dv * acc[i][j][rr]);
                }
            }
        }
    }
}

// ======= CSR aggregation layer 1, FEATURE-SPLIT (4 passes of 64 feats) =========
// h1 layout [4][M][64] bf16. blockIdx is pass-major: pass = blockIdx.x / nrb.
// Each pass's gather footprint is 12.8 MB (vs 51.2 MB whole), so the random
// gather re-references land in the per-XCD L2 far more often. Per-edge gather
// is exactly one 128 B line (1 ushort per lane). Dispatch order keeps passes
// temporally separated (resident window ~2K blocks << 25K blocks/pass).
// Summation order per feature is unchanged -> bit-identical results.

__global__ __launch_bounds__(256) void csr_agg1(const int* __restrict__ rp,
                                                const int* __restrict__ col,
                                                const float* __restrict__ dinv,
                                                const unsigned short* __restrict__ h1,
                                                const float* __restrict__ b1,
                                                unsigned short* __restrict__ act1,
                                                int M) {
    int w = threadIdx.x >> 6, lane = threadIdx.x & 63;
    int nrb = (M + 3) >> 2;               // row-blocks per pass
    int pass = blockIdx.x / nrb;
    int r = (blockIdx.x - pass * nrb) * 4 + w;
    if (r >= M) return;
    int start = r ? rp[r - 1] : 0;
    int end = rp[r];
    float dr = dinv[r];

    const unsigned short* hb = h1 + (size_t)pass * M * 64;  // feature-block base
    float a = b2f(hb[(size_t)r * 64 + lane]);               // self term

    int e = start;
    for (; e + 8 <= end; e += 8) {
        int s0 = col[e]     & PKMASK, s1 = col[e + 1] & PKMASK;
        int s2 = col[e + 2] & PKMASK, s3 = col[e + 3] & PKMASK;
        int s4 = col[e + 4] & PKMASK, s5 = col[e + 5] & PKMASK;
        int s6 = col[e + 6] & PKMASK, s7 = col[e + 7] & PKMASK;
        float q0 = b2f(hb[(size_t)s0 * 64 + lane]);
        float q1 = b2f(hb[(size_t)s1 * 64 + lane]);
        float q2 = b2f(hb[(size_t)s2 * 64 + lane]);
        float q3 = b2f(hb[(size_t)s3 * 64 + lane]);
        float q4 = b2f(hb[(size_t)s4 * 64 + lane]);
        float q5 = b2f(hb[(size_t)s5 * 64 + lane]);
        float q6 = b2f(hb[(size_t)s6 * 64 + lane]);
        float q7 = b2f(hb[(size_t)s7 * 64 + lane]);
        a += ((q0 + q1) + (q2 + q3)) + ((q4 + q5) + (q6 + q7));
    }
    for (; e < end; e++)
        a += b2f(hb[(size_t)(col[e] & PKMASK) * 64 + lane]);

    float bv = b1[pass * 64 + lane];
    act1[(size_t)r * F_HID + pass * 64 + lane] = f2b(fmaxf(dr * a + bv, 0.f));
}

// ===== MFMA GEMM2: h2s = dinv[m] * (act1 @ bf16(W2))  (M x 256)@(256 x 48pad) ===
// One wave per 16 rows; A frags straight from global (no LDS); W2t from L2.

__global__ __launch_bounds__(256) void mfma_gemm2(const unsigned short* __restrict__ act1,
                                                  const unsigned short* __restrict__ W2t,
                                                  const float* __restrict__ dinv,
                                                  float* __restrict__ h2, int M) {
    int wave = threadIdx.x >> 6, lane = threadIdx.x & 63;
    int quad = lane >> 4, l15 = lane & 15;
    int r0 = (blockIdx.x * 4 + wave) * 16;
    if (r0 >= M) return;

    f32x4 acc[3] = {};
    const unsigned short* arow = &act1[(size_t)(r0 + l15) * F_HID];
#pragma unroll
    for (int kt = 0; kt < F_HID; kt += 32) {
        bf16x8 af = *(const bf16x8*)&arow[kt + quad * 8];
#pragma unroll
        for (int j = 0; j < 3; j++) {
            bf16x8 bf = *(const bf16x8*)&W2t[(size_t)(j * 16 + l15) * F_HID + kt + quad * 8];
            acc[j] = __builtin_amdgcn_mfma_f32_16x16x32_bf16(af, bf, acc[j], 0, 0, 0);
        }
    }
    // C layout: col = l15 + j*16, row = quad*4 + rr; pre-scale by dinv[row]
#pragma unroll
    for (int j = 0; j < 3; j++) {
        int c = j * 16 + l15;
        if (c < N_CLS) {
#pragma unroll
            for (int rr = 0; rr < 4; rr++) {
                int r = r0 + quad * 4 + rr;
                h2[(size_t)r * N_CLS + c] = dinv[r] * acc[j][rr];
            }
        }
    }
}

// ===== CSR aggregation layer 2 (F=41, dinv-prescaled) + b2 + log_softmax ========

__global__ __launch_bounds__(256) void csr_agg2_lsm(const int* __restrict__ rp,
                                                    const int* __restrict__ col,
                                                    const float* __restrict__ dinv,
                                                    const float* __restrict__ h2,
                                                    const float* __restrict__ b2,
                                                    float* __restrict__ out, int M) {
    int w = threadIdx.x >> 6, lane = threadIdx.x & 63;
    int r = blockIdx.x * 4 + w;
    if (r >= M) return;
    int start = r ? rp[r - 1] : 0;
    int end = rp[r];
    float dr = dinv[r];

    float acc = 0.f;
    if (lane < N_CLS) acc = h2[(size_t)r * N_CLS + lane];  // self (prescaled)
    int e = start;
    for (; e + 4 <= end; e += 4) {
        int s0 = col[e] & PKMASK,     s1 = col[e + 1] & PKMASK;
        int s2 = col[e + 2] & PKMASK, s3 = col[e + 3] & PKMASK;
        if (lane < N_CLS) {
            float a0 = h2[(size_t)s0 * N_CLS + lane];
            float a1 = h2[(size_t)s1 * N_CLS + lane];
            float a2 = h2[(size_t)s2 * N_CLS + lane];
            float a3 = h2[(size_t)s3 * N_CLS + lane];
            acc += (a0 + a1) + (a2 + a3);
        }
    }
    for (; e < end; e++) {
        if (lane < N_CLS) acc += h2[(size_t)(col[e] & PKMASK) * N_CLS + lane];
    }
    float v = (lane < N_CLS) ? dr * acc + b2[lane] : -INFINITY;

    float m = v;
#pragma unroll
    for (int off = 32; off; off >>= 1) m = fmaxf(m, __shfl_xor(m, off));
    float ex = (lane < N_CLS) ? expf(v - m) : 0.f;
    float s = ex;
#pragma unroll
    for (int off = 32; off; off >>= 1) s += __shfl_xor(s, off);
    float ls = logf(s);
    if (lane < N_CLS) out[(size_t)r * N_CLS + lane] = v - m - ls;
}

// ================= launch =================

extern "C" void kernel_launch(void* const* d_in, const int* in_sizes, int n_in,
                              void* d_out, int out_size, void* d_ws, size_t ws_size,
                              hipStream_t stream) {
    const float* x  = (const float*)d_in[0];
    const int*   ei = (const int*)d_in[1];
    const float* W1 = (const float*)d_in[2];
    const float* b1 = (const float*)d_in[3];
    const float* W2 = (const float*)d_in[4];
    const float* b2 = (const float*)d_in[5];
    float* out = (float*)d_out;

    const int M = in_sizes[0] / F_IN;       // 100000
    const int E = in_sizes[1] / 2;          // 3200000
    const int* esrc = ei;
    const int* edst = ei + E;

    const int NBK = (M + 31) / 32;          // 3125 buckets of 32 dst nodes
    const int NW  = (E + CHUNK - 1) / CHUNK; // 196 edge chunks

    // workspace layout (bytes, 128-aligned)
    char* ws = (char*)d_ws;
    float*          dinv    = (float*)(ws);                         //     400,128
    int*            rp      = (int*)  (ws +    400128);             //     400,128
    int*            bbase   = (int*)  (ws +    800256);             //      12,544
    int*            btot    = (int*)  (ws +    812800);             //      12,544
    int*            hist_g  = (int*)  (ws +    825344);             //   2,450,048
    int*            packed  = (int*)  (ws +   3275392ull);          //  12,800,000
    int*            packed2 = (int*)  (ws +  16075392ull);          //  12,800,000
    unsigned short* W1t     = (unsigned short*)(ws + 28875392ull);  //     262,144
    unsigned short* W2t     = (unsigned short*)(ws + 29137536ull);  //      24,576
    unsigned short* h1      = (unsigned short*)(ws + 29162112ull);  //  51,200,000
    unsigned short* act1    = (unsigned short*)(ws + 80362112ull);  //  51,200,000
    float*          h2      = (float*)(ws + 131562112ull);          //  16,400,000

    // --- CSR build (bucketed, no global atomic storms) ---
    hist_pass<<<NW, 256, 0, stream>>>(edst, hist_g, E, NBK, NW);
    s1_btot<<<(NBK + 255) / 256, 256, 0, stream>>>(hist_g, btot, NBK, NW);
    s2_scan<<<1, 256, 0, stream>>>(btot, bbase, NBK);
    s3_rowscan<<<(NBK + 255) / 256, 256, 0, stream>>>(hist_g, bbase, NBK, NW);
    scatter_pass<<<NW, 256, 0, stream>>>(esrc, edst, hist_g, packed, E, NBK, NW);
    bucket_sort<<<NBK, 256, 0, stream>>>(packed, bbase, packed2, rp, dinv, M);

    // --- weight prep ---
    cvt_W1t<<<F_HID, 256, 0, stream>>>(W1, W1t);
    cvt_W2t<<<48, 256, 0, stream>>>(W2, W2t);

    // --- layer 1 ---
    mfma_gemm1<<<(M + 127) / 128, 512, 0, stream>>>(x, W1t, dinv, h1, M);
    {
        const int nrb = (M + 3) / 4;
        csr_agg1<<<4 * nrb, 256, 0, stream>>>(rp, packed2, dinv, h1, b1, act1, M);
    }

    // --- layer 2 ---
    mfma_gemm2<<<(M / 16 + 3) / 4, 256, 0, stream>>>(act1, W2t, dinv, h2, M);
    csr_agg2_lsm<<<(M + 3) / 4, 256, 0, stream>>>(rp, packed2, dinv, h2, b2, out, M);
}

// Round 4
// 931.562 us; speedup vs baseline: 1.1640x; 1.1640x over previous
//
#include <hip/hip_runtime.h>
#include <math.h>

// Problem constants (match reference file)
#define F_IN   512
#define F_HID  256
#define N_CLS  41

#define CHUNK  16384         // edges per workgroup in hist/scatter passes
#define MAXBK  3200          // LDS capacity for bucket arrays (NBK = ceil(M/32) = 3125)
#define PKMASK 0x1FFFF       // low 17 bits = src (M < 131072)
#define STILE_SH 12          // src locality tile = 4096 nodes
#define NKEY   1024          // 32 local-dst * 32 src-tiles

typedef __attribute__((ext_vector_type(8))) short     bf16x8;   // MFMA A/B frag
typedef __attribute__((ext_vector_type(8))) unsigned short u16x8;
typedef __attribute__((ext_vector_type(4))) float     f32x4;    // MFMA C/D frag

__device__ __forceinline__ float b2f(unsigned short u) {
    union { unsigned int i; float f; } v; v.i = ((unsigned int)u) << 16; return v.f;
}
__device__ __forceinline__ unsigned short f2b(float f) {  // RTN-even f32->bf16
    unsigned int u = __float_as_uint(f);
    u = (u + 0x7fffu + ((u >> 16) & 1u)) >> 16;
    return (unsigned short)u;
}

// ================= CSR build, atomic-storm-free =================
// Pass 1: per-WG LDS histogram over dst buckets (bucket = 32 nodes).
__global__ __launch_bounds__(256) void hist_pass(const int* __restrict__ edst,
                                                 int* __restrict__ hist_g,
                                                 int E, int NBK, int NW) {
    __shared__ int lh[MAXBK];
    int t = threadIdx.x, w = blockIdx.x;
    for (int b = t; b < NBK; b += 256) lh[b] = 0;
    __syncthreads();
    int e0 = w * CHUNK;
#pragma unroll 4
    for (int i = 0; i < CHUNK / 256; i++) {
        int e = e0 + i * 256 + t;
        if (e < E) atomicAdd(&lh[edst[e] >> 5], 1);
    }
    __syncthreads();
    for (int b = t; b < NBK; b += 256) hist_g[(size_t)b * NW + w] = lh[b];
}

// Pass 2a: bucket totals.
__global__ __launch_bounds__(256) void s1_btot(const int* __restrict__ hist_g,
                                               int* __restrict__ btot,
                                               int NBK, int NW) {
    int b = blockIdx.x * 256 + threadIdx.x;
    if (b >= NBK) return;
    const int* row = &hist_g[(size_t)b * NW];
    int s = 0;
    for (int w = 0; w < NW; w++) s += row[w];
    btot[b] = s;
}

// Pass 2b: exclusive scan of bucket totals -> bbase[0..NBK], bbase[NBK]=E.
__global__ __launch_bounds__(256) void s2_scan(const int* __restrict__ btot,
                                               int* __restrict__ bbase, int NBK) {
    __shared__ int ls[MAXBK];
    __shared__ int ss[257];
    int t = threadIdx.x;
    const int CH = (MAXBK + 255) / 256;  // 13
    for (int b = t; b < NBK; b += 256) ls[b] = btot[b];
    __syncthreads();
    int s = 0;
    for (int i = 0; i < CH; i++) {
        int idx = t * CH + i;
        if (idx < NBK) s += ls[idx];
    }
    ss[t] = s;
    __syncthreads();
    if (t == 0) {
        int run = 0;
        for (int i = 0; i < 256; i++) { int v = ss[i]; ss[i] = run; run += v; }
        ss[256] = run;
    }
    __syncthreads();
    int run = ss[t];
    for (int i = 0; i < CH; i++) {
        int idx = t * CH + i;
        if (idx < NBK) { int v = ls[idx]; ls[idx] = run; run += v; }
    }
    __syncthreads();
    for (int b = t; b < NBK; b += 256) bbase[b] = ls[b];
    if (t == 0) bbase[NBK] = ss[256];
}

// Pass 2c: per-bucket row exclusive scan -> per-WG write bases.
__global__ __launch_bounds__(256) void s3_rowscan(int* __restrict__ hist_g,
                                                  const int* __restrict__ bbase,
                                                  int NBK, int NW) {
    int b = blockIdx.x * 256 + threadIdx.x;
    if (b >= NBK) return;
    int* row = &hist_g[(size_t)b * NW];
    int run = bbase[b];
    for (int w = 0; w < NW; w++) { int v = row[w]; row[w] = run; run += v; }
}

// Pass 3: scatter edges into WG-private per-bucket ranges (no global atomics).
__global__ __launch_bounds__(256) void scatter_pass(const int* __restrict__ esrc,
                                                    const int* __restrict__ edst,
                                                    const int* __restrict__ hist_g,
                                                    int* __restrict__ packed,
                                                    int E, int NBK, int NW) {
    __shared__ int cur[MAXBK];
    int t = threadIdx.x, w = blockIdx.x;
    for (int b = t; b < NBK; b += 256) cur[b] = hist_g[(size_t)b * NW + w];
    __syncthreads();
    int e0 = w * CHUNK;
#pragma unroll 4
    for (int i = 0; i < CHUNK / 256; i++) {
        int e = e0 + i * 256 + t;
        if (e < E) {
            int d = edst[e];
            int pos = atomicAdd(&cur[d >> 5], 1);
            packed[pos] = esrc[e] | ((d & 31) << 17);
        }
    }
}

// Pass 4: per-bucket counting sort by (local dst, src tile) -> dst-sorted CSR
// (packed2), per-node row pointers rp (inclusive end), and dinv.
__global__ __launch_bounds__(256) void bucket_sort(const int* __restrict__ packed,
                                                   const int* __restrict__ bbase,
                                                   int* __restrict__ packed2,
                                                   int* __restrict__ rp,
                                                   float* __restrict__ dinv, int M) {
    __shared__ int cnt[NKEY];
    __shared__ int ss[256];
    __shared__ int rtot[32];
    int b = blockIdx.x, t = threadIdx.x;
    int start = bbase[b], end = bbase[b + 1];
    for (int i = t; i < NKEY; i += 256) cnt[i] = 0;
    __syncthreads();
    for (int e = start + t; e < end; e += 256) {
        int p = packed[e];
        atomicAdd(&cnt[(((p >> 17) & 31) << 5) | ((p & PKMASK) >> STILE_SH)], 1);
    }
    __syncthreads();
    // per-node totals -> rtot (for rp) and dinv
    if (t < 32) {
        int s = 0;
#pragma unroll
        for (int i = 0; i < 32; i++) s += cnt[(t << 5) + i];
        rtot[t] = s;
        int node = (b << 5) + t;
        if (node < M) dinv[node] = rsqrtf((float)s + 1.0f);
    }
    int i0 = t << 2;  // each thread owns 4 consecutive counters for the scan
    int v0 = cnt[i0], v1 = cnt[i0 + 1], v2 = cnt[i0 + 2], v3 = cnt[i0 + 3];
    ss[t] = v0 + v1 + v2 + v3;
    __syncthreads();
    if (t == 0) {
        int run = start;
#pragma unroll
        for (int i = 0; i < 32; i++) {
            run += rtot[i];
            int node = (b << 5) + i;
            if (node < M) rp[node] = run;  // inclusive end of row
        }
        run = start;
        for (int i = 0; i < 256; i++) { int v = ss[i]; ss[i] = run; run += v; }
    }
    __syncthreads();
    int run = ss[t];
    cnt[i0] = run; run += v0;
    cnt[i0 + 1] = run; run += v1;
    cnt[i0 + 2] = run; run += v2;
    cnt[i0 + 3] = run;
    __syncthreads();
    for (int e = start + t; e < end; e += 256) {
        int p = packed[e];
        int pos = atomicAdd(&cnt[(((p >> 17) & 31) << 5) | ((p & PKMASK) >> STILE_SH)], 1);
        packed2[pos] = p;
    }
}

// ========== weight prep: W1t[n][k]=bf16(W1[k][n]); W2t[n][k]=bf16(W2[k][n]) =====

__global__ __launch_bounds__(256) void cvt_W1t(const float* __restrict__ W1,
                                               unsigned short* __restrict__ W1t) {
    int n = blockIdx.x;  // 0..255
    for (int k = threadIdx.x; k < F_IN; k += 256)
        W1t[n * F_IN + k] = f2b(W1[(size_t)k * F_HID + n]);
}

__global__ __launch_bounds__(256) void cvt_W2t(const float* __restrict__ W2,
                                               unsigned short* __restrict__ W2t) {
    int n = blockIdx.x;   // 0..47 (padded)
    int k = threadIdx.x;  // 0..255
    W2t[n * F_HID + k] = (n < N_CLS) ? f2b(W2[(size_t)k * N_CLS + n])
                                     : (unsigned short)0;
}

// ====== MFMA GEMM1: h1s = dinv[m] * (bf16(x) @ bf16(W1))  (M x 512)@(512 x 256) ==
// 128x256 tile (full N in one block), BK=32, 512 threads = 8 waves (2x4 of 64x64).
// x read ONCE. Output pre-scaled by dinv[row], bf16, row-major [M][256].

__global__ __launch_bounds__(512) void mfma_gemm1(const float* __restrict__ A,
                                                  const unsigned short* __restrict__ Bt,
                                                  const float* __restrict__ dinv,
                                                  unsigned short* __restrict__ H1,
                                                  int M) {
    __shared__ unsigned short As[128 * 40];  // [m][k], row 40 shorts (pad)
    __shared__ unsigned short Bs[256 * 40];  // [n][k]
    int tid = threadIdx.x;
    int wave = tid >> 6, lane = tid & 63;
    int quad = lane >> 4, l15 = lane & 15;
    int m0 = blockIdx.x * 128;
    int wm = (wave & 1) * 64, wn = (wave >> 1) * 64;

    f32x4 acc[4][4] = {};

    int ar = tid >> 2, aq = tid & 3;   // A: row 0..127, 8-float quarter
    int bn = tid >> 1, bc = tid & 1;   // B: row(n) 0..255, chunk parity

    for (int k0 = 0; k0 < F_IN; k0 += 32) {
        // ---- stage A (f32 -> bf16) ----
        {
            int gm = m0 + ar;
            float4 v0, v1;
            if (gm < M) {
                const float4* ap = (const float4*)&A[(size_t)gm * F_IN + k0 + aq * 8];
                v0 = ap[0]; v1 = ap[1];
            } else {
                v0 = v1 = make_float4(0.f, 0.f, 0.f, 0.f);
            }
            u16x8 w;
            w[0]=f2b(v0.x); w[1]=f2b(v0.y); w[2]=f2b(v0.z); w[3]=f2b(v0.w);
            w[4]=f2b(v1.x); w[5]=f2b(v1.y); w[6]=f2b(v1.z); w[7]=f2b(v1.w);
            *(u16x8*)&As[ar * 40 + aq * 8] = w;
        }
        // ---- stage B (already bf16) ----
        {
            const unsigned short* bp = &Bt[(size_t)bn * F_IN + k0];
            *(u16x8*)&Bs[bn * 40 + bc * 8]       = *(const u16x8*)(bp + bc * 8);
            *(u16x8*)&Bs[bn * 40 + (bc + 2) * 8] = *(const u16x8*)(bp + bc * 8 + 16);
        }
        __syncthreads();
        bf16x8 af[4], bfr[4];
#pragma unroll
        for (int i = 0; i < 4; i++)
            af[i] = *(const bf16x8*)&As[(wm + i * 16 + l15) * 40 + quad * 8];
#pragma unroll
        for (int j = 0; j < 4; j++)
            bfr[j] = *(const bf16x8*)&Bs[(wn + j * 16 + l15) * 40 + quad * 8];
#pragma unroll
        for (int i = 0; i < 4; i++)
#pragma unroll
            for (int j = 0; j < 4; j++)
                acc[i][j] = __builtin_amdgcn_mfma_f32_16x16x32_bf16(
                    af[i], bfr[j], acc[i][j], 0, 0, 0);
        __syncthreads();
    }
    // ---- epilogue: C layout col=l15, row=quad*4+rr; pre-scale by dinv[row] ----
#pragma unroll
    for (int i = 0; i < 4; i++) {
#pragma unroll
        for (int rr = 0; rr < 4; rr++) {
            int gm = m0 + wm + i * 16 + quad * 4 + rr;
            if (gm < M) {
                float dv = dinv[gm];
#pragma unroll
                for (int j = 0; j < 4; j++) {
                    int gn = wn + j * 16 + l15;
                    H1[(size_t)gm * F_HID + gn] = f2b(dv * acc[i][j][rr]);
                }
            }
        }
    }
}

// ======= CSR aggregation layer 1 (F=256, bf16, dinv-prescaled) + bias + ReLU =====
// One wave per dst node; lane holds 4 bf16 feats (8 B/lane gather — DO NOT go
// thinner: round-3 showed 2 B/lane gathers cost 2.4x VALU for -18% fetch).
// Edge loop unrolled x16 to raise memory-level parallelism on the L2-miss path
// (VGPR budget <=64 keeps the 8-wave/SIMD occupancy cap). act1 stored with a
// nontemporal hint so 50 MB of streaming writes don't evict h1 gather lines.

__global__ __launch_bounds__(256) void csr_agg1(const int* __restrict__ rp,
                                                const int* __restrict__ col,
                                                const float* __restrict__ dinv,
                                                const unsigned short* __restrict__ h1,
                                                const float* __restrict__ b1,
                                                unsigned short* __restrict__ act1,
                                                int M) {
    int w = threadIdx.x >> 6, lane = threadIdx.x & 63;
    int r = blockIdx.x * 4 + w;
    if (r >= M) return;
    int start = r ? rp[r - 1] : 0;
    int end = rp[r];
    float dr = dinv[r];

    const ushort4* hv = (const ushort4*)h1;  // node stride 64 ushort4
    ushort4 v = hv[(size_t)r * 64 + lane];   // self term (already dinv[r]-scaled)
    float ax = b2f(v.x), ay = b2f(v.y), az = b2f(v.z), aw = b2f(v.w);

    int e = start;
    for (; e + 16 <= end; e += 16) {
        int s[16];
#pragma unroll
        for (int i = 0; i < 16; i++) s[i] = col[e + i] & PKMASK;
        ushort4 q[16];
#pragma unroll
        for (int i = 0; i < 16; i++) q[i] = hv[(size_t)s[i] * 64 + lane];
        float tx = 0.f, ty = 0.f, tz = 0.f, tw = 0.f;
#pragma unroll
        for (int i = 0; i < 16; i++) {
            tx += b2f(q[i].x); ty += b2f(q[i].y);
            tz += b2f(q[i].z); tw += b2f(q[i].w);
        }
        ax += tx; ay += ty; az += tz; aw += tw;
    }
    for (; e + 8 <= end; e += 8) {
        int s0 = col[e]     & PKMASK, s1 = col[e + 1] & PKMASK;
        int s2 = col[e + 2] & PKMASK, s3 = col[e + 3] & PKMASK;
        int s4 = col[e + 4] & PKMASK, s5 = col[e + 5] & PKMASK;
        int s6 = col[e + 6] & PKMASK, s7 = col[e + 7] & PKMASK;
        ushort4 q0 = hv[(size_t)s0 * 64 + lane];
        ushort4 q1 = hv[(size_t)s1 * 64 + lane];
        ushort4 q2 = hv[(size_t)s2 * 64 + lane];
        ushort4 q3 = hv[(size_t)s3 * 64 + lane];
        ushort4 q4 = hv[(size_t)s4 * 64 + lane];
        ushort4 q5 = hv[(size_t)s5 * 64 + lane];
        ushort4 q6 = hv[(size_t)s6 * 64 + lane];
        ushort4 q7 = hv[(size_t)s7 * 64 + lane];
        ax += ((b2f(q0.x) + b2f(q1.x)) + (b2f(q2.x) + b2f(q3.x)))
            + ((b2f(q4.x) + b2f(q5.x)) + (b2f(q6.x) + b2f(q7.x)));
        ay += ((b2f(q0.y) + b2f(q1.y)) + (b2f(q2.y) + b2f(q3.y)))
            + ((b2f(q4.y) + b2f(q5.y)) + (b2f(q6.y) + b2f(q7.y)));
        az += ((b2f(q0.z) + b2f(q1.z)) + (b2f(q2.z) + b2f(q3.z)))
            + ((b2f(q4.z) + b2f(q5.z)) + (b2f(q6.z) + b2f(q7.z)));
        aw += ((b2f(q0.w) + b2f(q1.w)) + (b2f(q2.w) + b2f(q3.w)))
            + ((b2f(q4.w) + b2f(q5.w)) + (b2f(q6.w) + b2f(q7.w)));
    }
    for (; e < end; e++) {
        ushort4 q = hv[(size_t)(col[e] & PKMASK) * 64 + lane];
        ax += b2f(q.x); ay += b2f(q.y); az += b2f(q.z); aw += b2f(q.w);
    }
    float4 bb = *(const float4*)&b1[lane * 4];
    ushort4 o;
    o.x = f2b(fmaxf(dr * ax + bb.x, 0.f));
    o.y = f2b(fmaxf(dr * ay + bb.y, 0.f));
    o.z = f2b(fmaxf(dr * az + bb.z, 0.f));
    o.w = f2b(fmaxf(dr * aw + bb.w, 0.f));
    union { ushort4 v; unsigned long long u; } cvt;
    cvt.v = o;
    __builtin_nontemporal_store(cvt.u,
        (unsigned long long*)&((ushort4*)act1)[(size_t)r * 64 + lane]);
}

// ===== MFMA GEMM2: h2b = bf16(dinv[m] * (act1 @ bf16(W2)))  row = ONE 128B line ==
// One wave per 16 rows; A frags straight from global (no LDS); W2t from L2.
// Output bf16, row stride 64 shorts (128 B aligned) -> csr_agg2's per-edge
// gather is exactly one L2 line and the gather footprint is 12.8 MB (vs 16.4).

__global__ __launch_bounds__(256) void mfma_gemm2(const unsigned short* __restrict__ act1,
                                                  const unsigned short* __restrict__ W2t,
                                                  const float* __restrict__ dinv,
                                                  unsigned short* __restrict__ h2b, int M) {
    int wave = threadIdx.x >> 6, lane = threadIdx.x & 63;
    int quad = lane >> 4, l15 = lane & 15;
    int r0 = (blockIdx.x * 4 + wave) * 16;
    if (r0 >= M) return;

    f32x4 acc[3] = {};
    const unsigned short* arow = &act1[(size_t)(r0 + l15) * F_HID];
#pragma unroll
    for (int kt = 0; kt < F_HID; kt += 32) {
        bf16x8 af = *(const bf16x8*)&arow[kt + quad * 8];
#pragma unroll
        for (int j = 0; j < 3; j++) {
            bf16x8 bf = *(const bf16x8*)&W2t[(size_t)(j * 16 + l15) * F_HID + kt + quad * 8];
            acc[j] = __builtin_amdgcn_mfma_f32_16x16x32_bf16(af, bf, acc[j], 0, 0, 0);
        }
    }
    // C layout: col = l15 + j*16, row = quad*4 + rr; pre-scale by dinv[row]
#pragma unroll
    for (int j = 0; j < 3; j++) {
        int c = j * 16 + l15;
        if (c < N_CLS) {
#pragma unroll
            for (int rr = 0; rr < 4; rr++) {
                int r = r0 + quad * 4 + rr;
                h2b[(size_t)r * 64 + c] = f2b(dinv[r] * acc[j][rr]);
            }
        }
    }
}

// ===== CSR aggregation layer 2 (F=41 bf16, dinv-prescaled) + b2 + log_softmax ===

__global__ __launch_bounds__(256) void csr_agg2_lsm(const int* __restrict__ rp,
                                                    const int* __restrict__ col,
                                                    const float* __restrict__ dinv,
                                                    const unsigned short* __restrict__ h2b,
                                                    const float* __restrict__ b2,
                                                    float* __restrict__ out, int M) {
    int w = threadIdx.x >> 6, lane = threadIdx.x & 63;
    int r = blockIdx.x * 4 + w;
    if (r >= M) return;
    int start = r ? rp[r - 1] : 0;
    int end = rp[r];
    float dr = dinv[r];

    float acc = 0.f;
    if (lane < N_CLS) acc = b2f(h2b[(size_t)r * 64 + lane]);  // self (prescaled)
    int e = start;
    for (; e + 8 <= end; e += 8) {
        int s0 = col[e]     & PKMASK, s1 = col[e + 1] & PKMASK;
        int s2 = col[e + 2] & PKMASK, s3 = col[e + 3] & PKMASK;
        int s4 = col[e + 4] & PKMASK, s5 = col[e + 5] & PKMASK;
        int s6 = col[e + 6] & PKMASK, s7 = col[e + 7] & PKMASK;
        if (lane < N_CLS) {
            float a0 = b2f(h2b[(size_t)s0 * 64 + lane]);
            float a1 = b2f(h2b[(size_t)s1 * 64 + lane]);
            float a2 = b2f(h2b[(size_t)s2 * 64 + lane]);
            float a3 = b2f(h2b[(size_t)s3 * 64 + lane]);
            float a4 = b2f(h2b[(size_t)s4 * 64 + lane]);
            float a5 = b2f(h2b[(size_t)s5 * 64 + lane]);
            float a6 = b2f(h2b[(size_t)s6 * 64 + lane]);
            float a7 = b2f(h2b[(size_t)s7 * 64 + lane]);
            acc += ((a0 + a1) + (a2 + a3)) + ((a4 + a5) + (a6 + a7));
        }
    }
    for (; e < end; e++) {
        if (lane < N_CLS) acc += b2f(h2b[(size_t)(col[e] & PKMASK) * 64 + lane]);
    }
    float v = (lane < N_CLS) ? dr * acc + b2[lane] : -INFINITY;

    float m = v;
#pragma unroll
    for (int off = 32; off; off >>= 1) m = fmaxf(m, __shfl_xor(m, off));
    float ex = (lane < N_CLS) ? expf(v - m) : 0.f;
    float s = ex;
#pragma unroll
    for (int off = 32; off; off >>= 1) s += __shfl_xor(s, off);
    float ls = logf(s);
    if (lane < N_CLS)
        __builtin_nontemporal_store(v - m - ls, &out[(size_t)r * N_CLS + lane]);
}

// ================= launch =================

extern "C" void kernel_launch(void* const* d_in, const int* in_sizes, int n_in,
                              void* d_out, int out_size, void* d_ws, size_t ws_size,
                              hipStream_t stream) {
    const float* x  = (const float*)d_in[0];
    const int*   ei = (const int*)d_in[1];
    const float* W1 = (const float*)d_in[2];
    const float* b1 = (const float*)d_in[3];
    const float* W2 = (const float*)d_in[4];
    const float* b2 = (const float*)d_in[5];
    float* out = (float*)d_out;

    const int M = in_sizes[0] / F_IN;       // 100000
    const int E = in_sizes[1] / 2;          // 3200000
    const int* esrc = ei;
    const int* edst = ei + E;

    const int NBK = (M + 31) / 32;          // 3125 buckets of 32 dst nodes
    const int NW  = (E + CHUNK - 1) / CHUNK; // 196 edge chunks

    // workspace layout (bytes, 128-aligned)
    char* ws = (char*)d_ws;
    float*          dinv    = (float*)(ws);                         //     400,128
    int*            rp      = (int*)  (ws +    400128);             //     400,128
    int*            bbase   = (int*)  (ws +    800256);             //      12,544
    int*            btot    = (int*)  (ws +    812800);             //      12,544
    int*            hist_g  = (int*)  (ws +    825344);             //   2,450,048
    int*            packed  = (int*)  (ws +   3275392ull);          //  12,800,000
    int*            packed2 = (int*)  (ws +  16075392ull);          //  12,800,000
    unsigned short* W1t     = (unsigned short*)(ws + 28875392ull);  //     262,144
    unsigned short* W2t     = (unsigned short*)(ws + 29137536ull);  //      24,576
    unsigned short* h1      = (unsigned short*)(ws + 29162112ull);  //  51,200,000
    unsigned short* act1    = (unsigned short*)(ws + 80362112ull);  //  51,200,000
    unsigned short* h2b     = (unsigned short*)(ws + 131562112ull); //  12,800,000

    // --- CSR build (bucketed, no global atomic storms) ---
    hist_pass<<<NW, 256, 0, stream>>>(edst, hist_g, E, NBK, NW);
    s1_btot<<<(NBK + 255) / 256, 256, 0, stream>>>(hist_g, btot, NBK, NW);
    s2_scan<<<1, 256, 0, stream>>>(btot, bbase, NBK);
    s3_rowscan<<<(NBK + 255) / 256, 256, 0, stream>>>(hist_g, bbase, NBK, NW);
    scatter_pass<<<NW, 256, 0, stream>>>(esrc, edst, hist_g, packed, E, NBK, NW);
    bucket_sort<<<NBK, 256, 0, stream>>>(packed, bbase, packed2, rp, dinv, M);

    // --- weight prep ---
    cvt_W1t<<<F_HID, 256, 0, stream>>>(W1, W1t);
    cvt_W2t<<<48, 256, 0, stream>>>(W2, W2t);

    // --- layer 1 ---
    mfma_gemm1<<<(M + 127) / 128, 512, 0, stream>>>(x, W1t, dinv, h1, M);
    csr_agg1<<<(M + 3) / 4, 256, 0, stream>>>(rp, packed2, dinv, h1, b1, act1, M);

    // --- layer 2 ---
    mfma_gemm2<<<(M / 16 + 3) / 4, 256, 0, stream>>>(act1, W2t, dinv, h2b, M);
    csr_agg2_lsm<<<(M + 3) / 4, 256, 0, stream>>>(rp, packed2, dinv, h2b, b2, out, M);
}

// Round 5
// 889.296 us; speedup vs baseline: 1.2193x; 1.0475x over previous
//
#include <hip/hip_runtime.h>
#include <math.h>

// Problem constants (match reference file)
#define F_IN   512
#define F_HID  256
#define N_CLS  41

#define CHUNK  16384         // edges per workgroup in hist/scatter passes
#define MAXBK  3200          // LDS capacity for bucket arrays (NBK = ceil(M/32) = 3125)
#define PKMASK 0x1FFFF       // low 17 bits = src (M < 131072)
#define STILE_SH 12          // src locality tile = 4096 nodes
#define NKEY   1024          // 32 local-dst * 32 src-tiles

typedef __attribute__((ext_vector_type(8))) short     bf16x8;   // MFMA A/B frag
typedef __attribute__((ext_vector_type(8))) unsigned short u16x8;
typedef __attribute__((ext_vector_type(4))) float     f32x4;    // MFMA C/D frag

__device__ __forceinline__ float b2f(unsigned short u) {
    union { unsigned int i; float f; } v; v.i = ((unsigned int)u) << 16; return v.f;
}
__device__ __forceinline__ unsigned short f2b(float f) {  // RTN-even f32->bf16
    unsigned int u = __float_as_uint(f);
    u = (u + 0x7fffu + ((u >> 16) & 1u)) >> 16;
    return (unsigned short)u;
}

// ================= CSR build, atomic-storm-free =================
// Pass 1: per-WG LDS histogram over dst buckets (bucket = 32 nodes).
__global__ __launch_bounds__(256) void hist_pass(const int* __restrict__ edst,
                                                 int* __restrict__ hist_g,
                                                 int E, int NBK, int NW) {
    __shared__ int lh[MAXBK];
    int t = threadIdx.x, w = blockIdx.x;
    for (int b = t; b < NBK; b += 256) lh[b] = 0;
    __syncthreads();
    int e0 = w * CHUNK;
#pragma unroll 4
    for (int i = 0; i < CHUNK / 256; i++) {
        int e = e0 + i * 256 + t;
        if (e < E) atomicAdd(&lh[edst[e] >> 5], 1);
    }
    __syncthreads();
    for (int b = t; b < NBK; b += 256) hist_g[(size_t)b * NW + w] = lh[b];
}

// Pass 2a: bucket totals.
__global__ __launch_bounds__(256) void s1_btot(const int* __restrict__ hist_g,
                                               int* __restrict__ btot,
                                               int NBK, int NW) {
    int b = blockIdx.x * 256 + threadIdx.x;
    if (b >= NBK) return;
    const int* row = &hist_g[(size_t)b * NW];
    int s = 0;
    for (int w = 0; w < NW; w++) s += row[w];
    btot[b] = s;
}

// Pass 2b: exclusive scan of bucket totals -> bbase[0..NBK], bbase[NBK]=E.
__global__ __launch_bounds__(256) void s2_scan(const int* __restrict__ btot,
                                               int* __restrict__ bbase, int NBK) {
    __shared__ int ls[MAXBK];
    __shared__ int ss[257];
    int t = threadIdx.x;
    const int CH = (MAXBK + 255) / 256;  // 13
    for (int b = t; b < NBK; b += 256) ls[b] = btot[b];
    __syncthreads();
    int s = 0;
    for (int i = 0; i < CH; i++) {
        int idx = t * CH + i;
        if (idx < NBK) s += ls[idx];
    }
    ss[t] = s;
    __syncthreads();
    if (t == 0) {
        int run = 0;
        for (int i = 0; i < 256; i++) { int v = ss[i]; ss[i] = run; run += v; }
        ss[256] = run;
    }
    __syncthreads();
    int run = ss[t];
    for (int i = 0; i < CH; i++) {
        int idx = t * CH + i;
        if (idx < NBK) { int v = ls[idx]; ls[idx] = run; run += v; }
    }
    __syncthreads();
    for (int b = t; b < NBK; b += 256) bbase[b] = ls[b];
    if (t == 0) bbase[NBK] = ss[256];
}

// Pass 2c: per-bucket row exclusive scan -> per-WG write bases.
__global__ __launch_bounds__(256) void s3_rowscan(int* __restrict__ hist_g,
                                                  const int* __restrict__ bbase,
                                                  int NBK, int NW) {
    int b = blockIdx.x * 256 + threadIdx.x;
    if (b >= NBK) return;
    int* row = &hist_g[(size_t)b * NW];
    int run = bbase[b];
    for (int w = 0; w < NW; w++) { int v = row[w]; row[w] = run; run += v; }
}

// Pass 3: scatter edges into WG-private per-bucket ranges (no global atomics).
__global__ __launch_bounds__(256) void scatter_pass(const int* __restrict__ esrc,
                                                    const int* __restrict__ edst,
                                                    const int* __restrict__ hist_g,
                                                    int* __restrict__ packed,
                                                    int E, int NBK, int NW) {
    __shared__ int cur[MAXBK];
    int t = threadIdx.x, w = blockIdx.x;
    for (int b = t; b < NBK; b += 256) cur[b] = hist_g[(size_t)b * NW + w];
    __syncthreads();
    int e0 = w * CHUNK;
#pragma unroll 4
    for (int i = 0; i < CHUNK / 256; i++) {
        int e = e0 + i * 256 + t;
        if (e < E) {
            int d = edst[e];
            int pos = atomicAdd(&cur[d >> 5], 1);
            packed[pos] = esrc[e] | ((d & 31) << 17);
        }
    }
}

// Pass 4: per-bucket counting sort by (local dst, src tile) -> dst-sorted CSR
// (packed2), per-node row pointers rp (inclusive end), and dinv.
__global__ __launch_bounds__(256) void bucket_sort(const int* __restrict__ packed,
                                                   const int* __restrict__ bbase,
                                                   int* __restrict__ packed2,
                                                   int* __restrict__ rp,
                                                   float* __restrict__ dinv, int M) {
    __shared__ int cnt[NKEY];
    __shared__ int ss[256];
    __shared__ int rtot[32];
    int b = blockIdx.x, t = threadIdx.x;
    int start = bbase[b], end = bbase[b + 1];
    for (int i = t; i < NKEY; i += 256) cnt[i] = 0;
    __syncthreads();
    for (int e = start + t; e < end; e += 256) {
        int p = packed[e];
        atomicAdd(&cnt[(((p >> 17) & 31) << 5) | ((p & PKMASK) >> STILE_SH)], 1);
    }
    __syncthreads();
    // per-node totals -> rtot (for rp) and dinv
    if (t < 32) {
        int s = 0;
#pragma unroll
        for (int i = 0; i < 32; i++) s += cnt[(t << 5) + i];
        rtot[t] = s;
        int node = (b << 5) + t;
        if (node < M) dinv[node] = rsqrtf((float)s + 1.0f);
    }
    int i0 = t << 2;  // each thread owns 4 consecutive counters for the scan
    int v0 = cnt[i0], v1 = cnt[i0 + 1], v2 = cnt[i0 + 2], v3 = cnt[i0 + 3];
    ss[t] = v0 + v1 + v2 + v3;
    __syncthreads();
    if (t == 0) {
        int run = start;
#pragma unroll
        for (int i = 0; i < 32; i++) {
            run += rtot[i];
            int node = (b << 5) + i;
            if (node < M) rp[node] = run;  // inclusive end of row
        }
        run = start;
        for (int i = 0; i < 256; i++) { int v = ss[i]; ss[i] = run; run += v; }
    }
    __syncthreads();
    int run = ss[t];
    cnt[i0] = run; run += v0;
    cnt[i0 + 1] = run; run += v1;
    cnt[i0 + 2] = run; run += v2;
    cnt[i0 + 3] = run;
    __syncthreads();
    for (int e = start + t; e < end; e += 256) {
        int p = packed[e];
        int pos = atomicAdd(&cnt[(((p >> 17) & 31) << 5) | ((p & PKMASK) >> STILE_SH)], 1);
        packed2[pos] = p;
    }
}

// ========== weight prep: W1t[n][k]=bf16(W1[k][n]); W2t[n][k]=bf16(W2[k][n]) =====

__global__ __launch_bounds__(256) void cvt_W1t(const float* __restrict__ W1,
                                               unsigned short* __restrict__ W1t) {
    int n = blockIdx.x;  // 0..255
    for (int k = threadIdx.x; k < F_IN; k += 256)
        W1t[n * F_IN + k] = f2b(W1[(size_t)k * F_HID + n]);
}

__global__ __launch_bounds__(256) void cvt_W2t(const float* __restrict__ W2,
                                               unsigned short* __restrict__ W2t) {
    int n = blockIdx.x;   // 0..47 (padded)
    int k = threadIdx.x;  // 0..255
    W2t[n * F_HID + k] = (n < N_CLS) ? f2b(W2[(size_t)k * N_CLS + n])
                                     : (unsigned short)0;
}

// ====== MFMA GEMM1: h1s = dinv[m] * (bf16(x) @ bf16(W1))  (M x 512)@(512 x 256) ==
// 128x256 tile (full N in one block), BK=32, 512 threads = 8 waves (2x4 of 64x64).
// x read ONCE. Output pre-scaled by dinv[row], bf16, row-major [M][256].

__global__ __launch_bounds__(512) void mfma_gemm1(const float* __restrict__ A,
                                                  const unsigned short* __restrict__ Bt,
                                                  const float* __restrict__ dinv,
                                                  unsigned short* __restrict__ H1,
                                                  int M) {
    __shared__ unsigned short As[128 * 40];  // [m][k], row 40 shorts (pad)
    __shared__ unsigned short Bs[256 * 40];  // [n][k]
    int tid = threadIdx.x;
    int wave = tid >> 6, lane = tid & 63;
    int quad = lane >> 4, l15 = lane & 15;
    int m0 = blockIdx.x * 128;
    int wm = (wave & 1) * 64, wn = (wave >> 1) * 64;

    f32x4 acc[4][4] = {};

    int ar = tid >> 2, aq = tid & 3;   // A: row 0..127, 8-float quarter
    int bn = tid >> 1, bc = tid & 1;   // B: row(n) 0..255, chunk parity

    for (int k0 = 0; k0 < F_IN; k0 += 32) {
        // ---- stage A (f32 -> bf16) ----
        {
            int gm = m0 + ar;
            float4 v0, v1;
            if (gm < M) {
                const float4* ap = (const float4*)&A[(size_t)gm * F_IN + k0 + aq * 8];
                v0 = ap[0]; v1 = ap[1];
            } else {
                v0 = v1 = make_float4(0.f, 0.f, 0.f, 0.f);
            }
            u16x8 w;
            w[0]=f2b(v0.x); w[1]=f2b(v0.y); w[2]=f2b(v0.z); w[3]=f2b(v0.w);
            w[4]=f2b(v1.x); w[5]=f2b(v1.y); w[6]=f2b(v1.z); w[7]=f2b(v1.w);
            *(u16x8*)&As[ar * 40 + aq * 8] = w;
        }
        // ---- stage B (already bf16) ----
        {
            const unsigned short* bp = &Bt[(size_t)bn * F_IN + k0];
            *(u16x8*)&Bs[bn * 40 + bc * 8]       = *(const u16x8*)(bp + bc * 8);
            *(u16x8*)&Bs[bn * 40 + (bc + 2) * 8] = *(const u16x8*)(bp + bc * 8 + 16);
        }
        __syncthreads();
        bf16x8 af[4], bfr[4];
#pragma unroll
        for (int i = 0; i < 4; i++)
            af[i] = *(const bf16x8*)&As[(wm + i * 16 + l15) * 40 + quad * 8];
#pragma unroll
        for (int j = 0; j < 4; j++)
            bfr[j] = *(const bf16x8*)&Bs[(wn + j * 16 + l15) * 40 + quad * 8];
#pragma unroll
        for (int i = 0; i < 4; i++)
#pragma unroll
            for (int j = 0; j < 4; j++)
                acc[i][j] = __builtin_amdgcn_mfma_f32_16x16x32_bf16(
                    af[i], bfr[j], acc[i][j], 0, 0, 0);
        __syncthreads();
    }
    // ---- epilogue: C layout col=l15, row=quad*4+rr; pre-scale by dinv[row] ----
#pragma unroll
    for (int i = 0; i < 4; i++) {
#pragma unroll
        for (int rr = 0; rr < 4; rr++) {
            int gm = m0 + wm + i * 16 + quad * 4 + rr;
            if (gm < M) {
                float dv = dinv[gm];
#pragma unroll
                for (int j = 0; j < 4; j++) {
                    int gn = wn + j * 16 + l15;
                    H1[(size_t)gm * F_HID + gn] = f2b(dv * acc[i][j][rr]);
                }
            }
        }
    }
}

// ======= FUSED agg1 + gemm2: aggregation + bias + ReLU + 256x48 projection =====
// One wave per dst node gathers h1 rows (8 B/lane — proven optimum; round-3
// showed thinner gathers lose 2.4x VALU for -18% fetch). The 4 aggregated rows
// of the block are staged in 2 KB LDS; wave 0 then projects them against
// L2-hot W2t with 24 MFMAs and writes h2b (bf16, 128 B rows) directly.
// This eliminates the act1 round-trip (50 MB write + 51 MB read) and the
// separate gemm2 dispatch entirely.

__global__ __launch_bounds__(256) void csr_agg1_fused(const int* __restrict__ rp,
                                                      const int* __restrict__ col,
                                                      const float* __restrict__ dinv,
                                                      const unsigned short* __restrict__ h1,
                                                      const float* __restrict__ b1,
                                                      const unsigned short* __restrict__ W2t,
                                                      unsigned short* __restrict__ h2b,
                                                      int M) {
    __shared__ unsigned short a4[4][256];  // block's 4 activated rows (bf16)
    int w = threadIdx.x >> 6, lane = threadIdx.x & 63;
    int r = blockIdx.x * 4 + w;
    bool valid = r < M;
    int start = 0, end = 0;
    float dr = 0.f;
    if (valid) {
        start = r ? rp[r - 1] : 0;
        end = rp[r];
        dr = dinv[r];
    }

    const ushort4* hv = (const ushort4*)h1;  // node stride 64 ushort4
    float ax = 0.f, ay = 0.f, az = 0.f, aw = 0.f;
    if (valid) {
        ushort4 v = hv[(size_t)r * 64 + lane];  // self term (dinv[r]-prescaled)
        ax = b2f(v.x); ay = b2f(v.y); az = b2f(v.z); aw = b2f(v.w);
    }

    int e = start;
    for (; e + 8 <= end; e += 8) {
        int s0 = col[e]     & PKMASK, s1 = col[e + 1] & PKMASK;
        int s2 = col[e + 2] & PKMASK, s3 = col[e + 3] & PKMASK;
        int s4 = col[e + 4] & PKMASK, s5 = col[e + 5] & PKMASK;
        int s6 = col[e + 6] & PKMASK, s7 = col[e + 7] & PKMASK;
        ushort4 q0 = hv[(size_t)s0 * 64 + lane];
        ushort4 q1 = hv[(size_t)s1 * 64 + lane];
        ushort4 q2 = hv[(size_t)s2 * 64 + lane];
        ushort4 q3 = hv[(size_t)s3 * 64 + lane];
        ushort4 q4 = hv[(size_t)s4 * 64 + lane];
        ushort4 q5 = hv[(size_t)s5 * 64 + lane];
        ushort4 q6 = hv[(size_t)s6 * 64 + lane];
        ushort4 q7 = hv[(size_t)s7 * 64 + lane];
        ax += ((b2f(q0.x) + b2f(q1.x)) + (b2f(q2.x) + b2f(q3.x)))
            + ((b2f(q4.x) + b2f(q5.x)) + (b2f(q6.x) + b2f(q7.x)));
        ay += ((b2f(q0.y) + b2f(q1.y)) + (b2f(q2.y) + b2f(q3.y)))
            + ((b2f(q4.y) + b2f(q5.y)) + (b2f(q6.y) + b2f(q7.y)));
        az += ((b2f(q0.z) + b2f(q1.z)) + (b2f(q2.z) + b2f(q3.z)))
            + ((b2f(q4.z) + b2f(q5.z)) + (b2f(q6.z) + b2f(q7.z)));
        aw += ((b2f(q0.w) + b2f(q1.w)) + (b2f(q2.w) + b2f(q3.w)))
            + ((b2f(q4.w) + b2f(q5.w)) + (b2f(q6.w) + b2f(q7.w)));
    }
    for (; e < end; e++) {
        ushort4 q = hv[(size_t)(col[e] & PKMASK) * 64 + lane];
        ax += b2f(q.x); ay += b2f(q.y); az += b2f(q.z); aw += b2f(q.w);
    }
    if (valid) {
        float4 bb = *(const float4*)&b1[lane * 4];
        ushort4 o;
        o.x = f2b(fmaxf(dr * ax + bb.x, 0.f));
        o.y = f2b(fmaxf(dr * ay + bb.y, 0.f));
        o.z = f2b(fmaxf(dr * az + bb.z, 0.f));
        o.w = f2b(fmaxf(dr * aw + bb.w, 0.f));
        *(ushort4*)&a4[w][lane * 4] = o;
    }
    __syncthreads();
    // ---- wave 0: project the block's 4 rows with MFMA (rows 4-15 duplicate) --
    if (w == 0) {
        int quad = lane >> 4, l15 = lane & 15;
        int rr4 = l15 & 3;  // clamp A row to 0..3; dup rows' outputs discarded
        f32x4 acc[3] = {};
#pragma unroll
        for (int kt = 0; kt < F_HID; kt += 32) {
            bf16x8 af = *(const bf16x8*)&a4[rr4][kt + quad * 8];
#pragma unroll
            for (int j = 0; j < 3; j++) {
                bf16x8 bf = *(const bf16x8*)&W2t[(size_t)(j * 16 + l15) * F_HID + kt + quad * 8];
                acc[j] = __builtin_amdgcn_mfma_f32_16x16x32_bf16(af, bf, acc[j], 0, 0, 0);
            }
        }
        // D layout: col=l15+j*16, row=quad*4+rr -> valid block rows live in quad 0
        if (quad == 0) {
#pragma unroll
            for (int rr = 0; rr < 4; rr++) {
                int gr = blockIdx.x * 4 + rr;
                if (gr < M) {
                    float dv = dinv[gr];
#pragma unroll
                    for (int j = 0; j < 3; j++) {
                        int c = j * 16 + l15;  // 0..47; cols 41..47 are zeros
                        h2b[(size_t)gr * 64 + c] = f2b(dv * acc[j][rr]);
                    }
                }
            }
        }
    }
}

// ===== CSR aggregation layer 2 (F=41 bf16, dinv-prescaled) + b2 + log_softmax ===
// 4 edges per wave: group g = lanes 16g..16g+15 handles edge e+g; lanes l15<11
// load ushort4 (8 B/lane, classes 4*l15..4*l15+3; padding classes 41..47 are
// zero in h2b). 4x fewer VMEM instructions than the 2 B/lane form. Cross-group
// combine is 2 shuffles per accumulator.

__global__ __launch_bounds__(256) void csr_agg2_lsm(const int* __restrict__ rp,
                                                    const int* __restrict__ col,
                                                    const float* __restrict__ dinv,
                                                    const unsigned short* __restrict__ h2b,
                                                    const float* __restrict__ b2,
                                                    float* __restrict__ out, int M) {
    int w = threadIdx.x >> 6, lane = threadIdx.x & 63;
    int r = blockIdx.x * 4 + w;
    if (r >= M) return;
    int start = r ? rp[r - 1] : 0;
    int end = rp[r];
    float dr = dinv[r];
    int g = lane >> 4, l15 = lane & 15;
    bool act = l15 < 11;  // 11 lanes x 4 classes = 44 >= 41 (+3 zero pads)

    const ushort4* hq = (const ushort4*)h2b;  // row stride 16 ushort4
    float a0 = 0.f, a1 = 0.f, a2 = 0.f, a3 = 0.f;
    if (g == 0 && act) {  // self term (prescaled)
        ushort4 q = hq[(size_t)r * 16 + l15];
        a0 = b2f(q.x); a1 = b2f(q.y); a2 = b2f(q.z); a3 = b2f(q.w);
    }
    int e = start;
    for (; e + 8 <= end; e += 8) {
        int sA = col[e + g] & PKMASK;
        int sB = col[e + 4 + g] & PKMASK;
        if (act) {
            ushort4 qA = hq[(size_t)sA * 16 + l15];
            ushort4 qB = hq[(size_t)sB * 16 + l15];
            a0 += b2f(qA.x) + b2f(qB.x);
            a1 += b2f(qA.y) + b2f(qB.y);
            a2 += b2f(qA.z) + b2f(qB.z);
            a3 += b2f(qA.w) + b2f(qB.w);
        }
    }
    if (e + g < end && act) {
        ushort4 q = hq[(size_t)(col[e + g] & PKMASK) * 16 + l15];
        a0 += b2f(q.x); a1 += b2f(q.y); a2 += b2f(q.z); a3 += b2f(q.w);
    }
    if (e + 4 + g < end && act) {
        ushort4 q = hq[(size_t)(col[e + 4 + g] & PKMASK) * 16 + l15];
        a0 += b2f(q.x); a1 += b2f(q.y); a2 += b2f(q.z); a3 += b2f(q.w);
    }
    // combine the 4 groups (lanes l, l^16, l^32, l^48)
    a0 += __shfl_xor(a0, 16); a0 += __shfl_xor(a0, 32);
    a1 += __shfl_xor(a1, 16); a1 += __shfl_xor(a1, 32);
    a2 += __shfl_xor(a2, 16); a2 += __shfl_xor(a2, 32);
    a3 += __shfl_xor(a3, 16); a3 += __shfl_xor(a3, 32);

    int c0 = l15 * 4;
    int cc = c0 < N_CLS ? c0 : N_CLS - 1;   // clamped bias index (in-bounds)
    float4 bb = make_float4(b2[cc], b2[(c0 + 1 < N_CLS) ? c0 + 1 : N_CLS - 1],
                            b2[(c0 + 2 < N_CLS) ? c0 + 2 : N_CLS - 1],
                            b2[(c0 + 3 < N_CLS) ? c0 + 3 : N_CLS - 1]);
    float v0 = (c0     < N_CLS) ? dr * a0 + bb.x : -INFINITY;
    float v1 = (c0 + 1 < N_CLS) ? dr * a1 + bb.y : -INFINITY;
    float v2 = (c0 + 2 < N_CLS) ? dr * a2 + bb.z : -INFINITY;
    float v3 = (c0 + 3 < N_CLS) ? dr * a3 + bb.w : -INFINITY;

    float m = fmaxf(fmaxf(v0, v1), fmaxf(v2, v3));
#pragma unroll
    for (int off = 1; off < 16; off <<= 1) m = fmaxf(m, __shfl_xor(m, off));
    float s = expf(v0 - m) + expf(v1 - m) + expf(v2 - m) + expf(v3 - m);
#pragma unroll
    for (int off = 1; off < 16; off <<= 1) s += __shfl_xor(s, off);
    float ls = m + logf(s);

    if (g == 0) {
        float* orow = &out[(size_t)r * N_CLS];
        if (c0 < N_CLS)     __builtin_nontemporal_store(v0 - ls, &orow[c0]);
        if (c0 + 1 < N_CLS) __builtin_nontemporal_store(v1 - ls, &orow[c0 + 1]);
        if (c0 + 2 < N_CLS) __builtin_nontemporal_store(v2 - ls, &orow[c0 + 2]);
        if (c0 + 3 < N_CLS) __builtin_nontemporal_store(v3 - ls, &orow[c0 + 3]);
    }
}

// ================= launch =================

extern "C" void kernel_launch(void* const* d_in, const int* in_sizes, int n_in,
                              void* d_out, int out_size, void* d_ws, size_t ws_size,
                              hipStream_t stream) {
    const float* x  = (const float*)d_in[0];
    const int*   ei = (const int*)d_in[1];
    const float* W1 = (const float*)d_in[2];
    const float* b1 = (const float*)d_in[3];
    const float* W2 = (const float*)d_in[4];
    const float* b2 = (const float*)d_in[5];
    float* out = (float*)d_out;

    const int M = in_sizes[0] / F_IN;       // 100000
    const int E = in_sizes[1] / 2;          // 3200000
    const int* esrc = ei;
    const int* edst = ei + E;

    const int NBK = (M + 31) / 32;          // 3125 buckets of 32 dst nodes
    const int NW  = (E + CHUNK - 1) / CHUNK; // 196 edge chunks

    // workspace layout (bytes, 128-aligned)
    char* ws = (char*)d_ws;
    float*          dinv    = (float*)(ws);                         //     400,128
    int*            rp      = (int*)  (ws +    400128);             //     400,128
    int*            bbase   = (int*)  (ws +    800256);             //      12,544
    int*            btot    = (int*)  (ws +    812800);             //      12,544
    int*            hist_g  = (int*)  (ws +    825344);             //   2,450,048
    int*            packed  = (int*)  (ws +   3275392ull);          //  12,800,000
    int*            packed2 = (int*)  (ws +  16075392ull);          //  12,800,000
    unsigned short* W1t     = (unsigned short*)(ws + 28875392ull);  //     262,144
    unsigned short* W2t     = (unsigned short*)(ws + 29137536ull);  //      24,576
    unsigned short* h1      = (unsigned short*)(ws + 29162112ull);  //  51,200,000
    unsigned short* h2b     = (unsigned short*)(ws + 80362112ull);  //  12,800,000

    // --- CSR build (bucketed, no global atomic storms) ---
    hist_pass<<<NW, 256, 0, stream>>>(edst, hist_g, E, NBK, NW);
    s1_btot<<<(NBK + 255) / 256, 256, 0, stream>>>(hist_g, btot, NBK, NW);
    s2_scan<<<1, 256, 0, stream>>>(btot, bbase, NBK);
    s3_rowscan<<<(NBK + 255) / 256, 256, 0, stream>>>(hist_g, bbase, NBK, NW);
    scatter_pass<<<NW, 256, 0, stream>>>(esrc, edst, hist_g, packed, E, NBK, NW);
    bucket_sort<<<NBK, 256, 0, stream>>>(packed, bbase, packed2, rp, dinv, M);

    // --- weight prep ---
    cvt_W1t<<<F_HID, 256, 0, stream>>>(W1, W1t);
    cvt_W2t<<<48, 256, 0, stream>>>(W2, W2t);

    // --- layer 1 (+ fused layer-2 linear) ---
    mfma_gemm1<<<(M + 127) / 128, 512, 0, stream>>>(x, W1t, dinv, h1, M);
    csr_agg1_fused<<<(M + 3) / 4, 256, 0, stream>>>(rp, packed2, dinv, h1, b1,
                                                    W2t, h2b, M);

    // --- layer 2 aggregation + log_softmax ---
    csr_agg2_lsm<<<(M + 3) / 4, 256, 0, stream>>>(rp, packed2, dinv, h2b, b2, out, M);
}

// Round 6
// 852.077 us; speedup vs baseline: 1.2726x; 1.0437x over previous
//
#include <hip/hip_runtime.h>
#include <math.h>

// Problem constants (match reference file)
#define F_IN   512
#define F_HID  256
#define N_CLS  41

#define CHUNK  16384         // edges per workgroup in hist/scatter passes
#define MAXBK  3200          // LDS capacity for bucket arrays (NBK = ceil(M/32) = 3125)
#define PKMASK 0x1FFFF       // low 17 bits = src (M < 131072)
#define STILE_SH 12          // src locality tile = 4096 nodes
#define NKEY   1024          // 32 local-dst * 32 src-tiles

typedef __attribute__((ext_vector_type(8))) short     bf16x8;   // MFMA A/B frag
typedef __attribute__((ext_vector_type(8))) unsigned short u16x8;
typedef __attribute__((ext_vector_type(4))) float     f32x4;    // MFMA C/D frag

__device__ __forceinline__ float b2f(unsigned short u) {
    union { unsigned int i; float f; } v; v.i = ((unsigned int)u) << 16; return v.f;
}
__device__ __forceinline__ unsigned short f2b(float f) {  // RTN-even f32->bf16
    unsigned int u = __float_as_uint(f);
    u = (u + 0x7fffu + ((u >> 16) & 1u)) >> 16;
    return (unsigned short)u;
}

// ================= CSR build, atomic-storm-free =================
// hist_g layout is WG-MAJOR [w][b]: every producer/consumer below touches it
// with lane-contiguous b -> fully coalesced (the old [b][w] layout cost
// ~150 MB of strided line traffic for 2.45 MB of data).

// Pass 1: per-WG LDS histogram over dst buckets (bucket = 32 nodes).
__global__ __launch_bounds__(256) void hist_pass(const int* __restrict__ edst,
                                                 int* __restrict__ hist_g,
                                                 int E, int NBK, int NW) {
    __shared__ int lh[MAXBK];
    int t = threadIdx.x, w = blockIdx.x;
    for (int b = t; b < NBK; b += 256) lh[b] = 0;
    __syncthreads();
    int e0 = w * CHUNK;
#pragma unroll 4
    for (int i = 0; i < CHUNK / 256; i++) {
        int e = e0 + i * 256 + t;
        if (e < E) atomicAdd(&lh[edst[e] >> 5], 1);
    }
    __syncthreads();
    for (int b = t; b < NBK; b += 256) hist_g[(size_t)w * NBK + b] = lh[b];
}

// Pass 2a: bucket totals (coalesced: consecutive lanes = consecutive b).
__global__ __launch_bounds__(256) void s1_btot(const int* __restrict__ hist_g,
                                               int* __restrict__ btot,
                                               int NBK, int NW) {
    int b = blockIdx.x * 256 + threadIdx.x;
    if (b >= NBK) return;
    int s = 0;
    for (int w = 0; w < NW; w++) s += hist_g[(size_t)w * NBK + b];
    btot[b] = s;
}

// Pass 2b: exclusive scan of bucket totals -> bbase[0..NBK], bbase[NBK]=E.
// Parallel Hillis-Steele scan (replaces the serial 256-iteration t0 loop).
__global__ __launch_bounds__(256) void s2_scan(const int* __restrict__ btot,
                                               int* __restrict__ bbase, int NBK) {
    __shared__ int ls[MAXBK];
    __shared__ int ss[256];
    int t = threadIdx.x;
    const int CH = (MAXBK + 255) / 256;  // 13
    for (int b = t; b < NBK; b += 256) ls[b] = btot[b];
    __syncthreads();
    int s = 0;
    for (int i = 0; i < CH; i++) {
        int idx = t * CH + i;
        if (idx < NBK) s += ls[idx];
    }
    int own = s;
    ss[t] = own;
    __syncthreads();
#pragma unroll
    for (int off = 1; off < 256; off <<= 1) {
        int add = (t >= off) ? ss[t - off] : 0;
        __syncthreads();
        ss[t] += add;
        __syncthreads();
    }
    int run = ss[t] - own;  // exclusive prefix of this thread's segment
    for (int i = 0; i < CH; i++) {
        int idx = t * CH + i;
        if (idx < NBK) { int v = ls[idx]; ls[idx] = run; run += v; }
    }
    __syncthreads();
    for (int b = t; b < NBK; b += 256) bbase[b] = ls[b];
    if (t == 0) bbase[NBK] = ss[255];
}

// Pass 2c: per-bucket row exclusive scan -> per-WG write bases (coalesced).
__global__ __launch_bounds__(256) void s3_rowscan(int* __restrict__ hist_g,
                                                  const int* __restrict__ bbase,
                                                  int NBK, int NW) {
    int b = blockIdx.x * 256 + threadIdx.x;
    if (b >= NBK) return;
    int run = bbase[b];
    for (int w = 0; w < NW; w++) {
        int v = hist_g[(size_t)w * NBK + b];
        hist_g[(size_t)w * NBK + b] = run;
        run += v;
    }
}

// Pass 3: scatter edges into WG-private per-bucket ranges (no global atomics).
__global__ __launch_bounds__(256) void scatter_pass(const int* __restrict__ esrc,
                                                    const int* __restrict__ edst,
                                                    const int* __restrict__ hist_g,
                                                    int* __restrict__ packed,
                                                    int E, int NBK, int NW) {
    __shared__ int cur[MAXBK];
    int t = threadIdx.x, w = blockIdx.x;
    for (int b = t; b < NBK; b += 256) cur[b] = hist_g[(size_t)w * NBK + b];
    __syncthreads();
    int e0 = w * CHUNK;
#pragma unroll 4
    for (int i = 0; i < CHUNK / 256; i++) {
        int e = e0 + i * 256 + t;
        if (e < E) {
            int d = edst[e];
            int pos = atomicAdd(&cur[d >> 5], 1);
            packed[pos] = esrc[e] | ((d & 31) << 17);
        }
    }
}

// Pass 4: per-bucket counting sort by (local dst, src tile) -> dst-sorted CSR
// (packed2), per-node row pointers rp (inclusive end), and dinv.
// Scans parallelized: 256-entry Hillis-Steele in LDS + 32-entry wave shuffle.
__global__ __launch_bounds__(256) void bucket_sort(const int* __restrict__ packed,
                                                   const int* __restrict__ bbase,
                                                   int* __restrict__ packed2,
                                                   int* __restrict__ rp,
                                                   float* __restrict__ dinv, int M) {
    __shared__ int cnt[NKEY];
    __shared__ int ss[256];
    __shared__ int rtot[32];
    int b = blockIdx.x, t = threadIdx.x;
    int lane = t & 63;
    int start = bbase[b], end = bbase[b + 1];
    for (int i = t; i < NKEY; i += 256) cnt[i] = 0;
    __syncthreads();
    for (int e = start + t; e < end; e += 256) {
        int p = packed[e];
        atomicAdd(&cnt[(((p >> 17) & 31) << 5) | ((p & PKMASK) >> STILE_SH)], 1);
    }
    __syncthreads();
    // per-node totals -> rtot (for rp) and dinv; each thread t<32 writes rtot[t]
    if (t < 32) {
        int s = 0;
#pragma unroll
        for (int i = 0; i < 32; i++) s += cnt[(t << 5) + i];
        rtot[t] = s;
        int node = (b << 5) + t;
        if (node < M) dinv[node] = rsqrtf((float)s + 1.0f);
    }
    int i0 = t << 2;  // each thread owns 4 consecutive counters
    int v0 = cnt[i0], v1 = cnt[i0 + 1], v2 = cnt[i0 + 2], v3 = cnt[i0 + 3];
    int own = v0 + v1 + v2 + v3;
    ss[t] = own;
    __syncthreads();
#pragma unroll
    for (int off = 1; off < 256; off <<= 1) {
        int add = (t >= off) ? ss[t - off] : 0;
        __syncthreads();
        ss[t] += add;
        __syncthreads();
    }
    // rp: wave 0 shuffle-scan of rtot (each lane<32 reads its OWN rtot entry)
    if (t < 64) {
        int rv = (lane < 32) ? rtot[lane] : 0;
#pragma unroll
        for (int off = 1; off < 32; off <<= 1) {
            int n = __shfl_up(rv, off);
            if (lane >= off) rv += n;
        }
        if (lane < 32) {
            int node = (b << 5) + lane;
            if (node < M) rp[node] = start + rv;  // inclusive end of row
        }
    }
    int run = start + ss[t] - own;  // exclusive base for this thread's 4 keys
    cnt[i0] = run; run += v0;
    cnt[i0 + 1] = run; run += v1;
    cnt[i0 + 2] = run; run += v2;
    cnt[i0 + 3] = run;
    __syncthreads();
    for (int e = start + t; e < end; e += 256) {
        int p = packed[e];
        int pos = atomicAdd(&cnt[(((p >> 17) & 31) << 5) | ((p & PKMASK) >> STILE_SH)], 1);
        packed2[pos] = p;
    }
}

// ========== weight prep: W1t[n][k]=bf16(W1[k][n]) via LDS tile transpose =======
// 64k x 64n tiles; both global read and write fully coalesced.

__global__ __launch_bounds__(256) void cvt_W1t(const float* __restrict__ W1,
                                               unsigned short* __restrict__ W1t) {
    __shared__ unsigned short tl[64][72];   // padded to break bank alignment
    int kt = (blockIdx.x >> 2) << 6;        // 8 k-tiles
    int nt = (blockIdx.x & 3) << 6;         // 4 n-tiles
    int t = threadIdx.x;
    int kr = t >> 2, nseg = (t & 3) << 4;   // load: row kr, 16-col segment
    const float4* src = (const float4*)&W1[(size_t)(kt + kr) * F_HID + nt + nseg];
    float4 f0 = src[0], f1 = src[1], f2 = src[2], f3 = src[3];
    unsigned short* d = &tl[kr][nseg];
    d[0]=f2b(f0.x); d[1]=f2b(f0.y); d[2]=f2b(f0.z); d[3]=f2b(f0.w);
    d[4]=f2b(f1.x); d[5]=f2b(f1.y); d[6]=f2b(f1.z); d[7]=f2b(f1.w);
    d[8]=f2b(f2.x); d[9]=f2b(f2.y); d[10]=f2b(f2.z); d[11]=f2b(f2.w);
    d[12]=f2b(f3.x); d[13]=f2b(f3.y); d[14]=f2b(f3.z); d[15]=f2b(f3.w);
    __syncthreads();
    int nr = t >> 2, kseg = (t & 3) << 4;   // store: row nr, 16-k segment
    u16x8 o0, o1;
#pragma unroll
    for (int j = 0; j < 8; j++) o0[j] = tl[kseg + j][nr];
#pragma unroll
    for (int j = 0; j < 8; j++) o1[j] = tl[kseg + 8 + j][nr];
    unsigned short* dst = &W1t[(size_t)(nt + nr) * F_IN + kt + kseg];
    *(u16x8*)dst = o0;
    *(u16x8*)(dst + 8) = o1;
}

__global__ __launch_bounds__(256) void cvt_W2t(const float* __restrict__ W2,
                                               unsigned short* __restrict__ W2t) {
    int n = blockIdx.x;   // 0..47 (padded)
    int k = threadIdx.x;  // 0..255
    W2t[n * F_HID + k] = (n < N_CLS) ? f2b(W2[(size_t)k * N_CLS + n])
                                     : (unsigned short)0;
}

// ====== MFMA GEMM1: h1s = dinv[m] * (bf16(x) @ bf16(W1))  (M x 512)@(512 x 256) ==
// 128x256 tile (full N in one block), BK=32, 512 threads = 8 waves (2x4 of 64x64).
// x read ONCE. Output pre-scaled by dinv[row], bf16, row-major [M][256].

__global__ __launch_bounds__(512) void mfma_gemm1(const float* __restrict__ A,
                                                  const unsigned short* __restrict__ Bt,
                                                  const float* __restrict__ dinv,
                                                  unsigned short* __restrict__ H1,
                                                  int M) {
    __shared__ unsigned short As[128 * 40];  // [m][k], row 40 shorts (pad)
    __shared__ unsigned short Bs[256 * 40];  // [n][k]
    int tid = threadIdx.x;
    int wave = tid >> 6, lane = tid & 63;
    int quad = lane >> 4, l15 = lane & 15;
    int m0 = blockIdx.x * 128;
    int wm = (wave & 1) * 64, wn = (wave >> 1) * 64;

    f32x4 acc[4][4] = {};

    int ar = tid >> 2, aq = tid & 3;   // A: row 0..127, 8-float quarter
    int bn = tid >> 1, bc = tid & 1;   // B: row(n) 0..255, chunk parity

    for (int k0 = 0; k0 < F_IN; k0 += 32) {
        // ---- stage A (f32 -> bf16) ----
        {
            int gm = m0 + ar;
            float4 v0, v1;
            if (gm < M) {
                const float4* ap = (const float4*)&A[(size_t)gm * F_IN + k0 + aq * 8];
                v0 = ap[0]; v1 = ap[1];
            } else {
                v0 = v1 = make_float4(0.f, 0.f, 0.f, 0.f);
            }
            u16x8 w;
            w[0]=f2b(v0.x); w[1]=f2b(v0.y); w[2]=f2b(v0.z); w[3]=f2b(v0.w);
            w[4]=f2b(v1.x); w[5]=f2b(v1.y); w[6]=f2b(v1.z); w[7]=f2b(v1.w);
            *(u16x8*)&As[ar * 40 + aq * 8] = w;
        }
        // ---- stage B (already bf16) ----
        {
            const unsigned short* bp = &Bt[(size_t)bn * F_IN + k0];
            *(u16x8*)&Bs[bn * 40 + bc * 8]       = *(const u16x8*)(bp + bc * 8);
            *(u16x8*)&Bs[bn * 40 + (bc + 2) * 8] = *(const u16x8*)(bp + bc * 8 + 16);
        }
        __syncthreads();
        bf16x8 af[4], bfr[4];
#pragma unroll
        for (int i = 0; i < 4; i++)
            af[i] = *(const bf16x8*)&As[(wm + i * 16 + l15) * 40 + quad * 8];
#pragma unroll
        for (int j = 0; j < 4; j++)
            bfr[j] = *(const bf16x8*)&Bs[(wn + j * 16 + l15) * 40 + quad * 8];
#pragma unroll
        for (int i = 0; i < 4; i++)
#pragma unroll
            for (int j = 0; j < 4; j++)
                acc[i][j] = __builtin_amdgcn_mfma_f32_16x16x32_bf16(
                    af[i], bfr[j], acc[i][j], 0, 0, 0);
        __syncthreads();
    }
    // ---- epilogue: C layout col=l15, row=quad*4+rr; pre-scale by dinv[row] ----
#pragma unroll
    for (int i = 0; i < 4; i++) {
#pragma unroll
        for (int rr = 0; rr < 4; rr++) {
            int gm = m0 + wm + i * 16 + quad * 4 + rr;
            if (gm < M) {
                float dv = dinv[gm];
#pragma unroll
                for (int j = 0; j < 4; j++) {
                    int gn = wn + j * 16 + l15;
                    H1[(size_t)gm * F_HID + gn] = f2b(dv * acc[i][j][rr]);
                }
            }
        }
    }
}

// ======= FUSED agg1 + gemm2: aggregation + bias + ReLU + 256x48 projection =====
// One wave per dst node gathers h1 rows (8 B/lane — proven optimum; round-3
// showed thinner gathers lose 2.4x VALU for -18% fetch). The 4 aggregated rows
// of the block are staged in 2 KB LDS; wave 0 then projects them against
// L2-hot W2t with 24 MFMAs and writes h2b (bf16, 128 B rows) directly.

__global__ __launch_bounds__(256) void csr_agg1_fused(const int* __restrict__ rp,
                                                      const int* __restrict__ col,
                                                      const float* __restrict__ dinv,
                                                      const unsigned short* __restrict__ h1,
                                                      const float* __restrict__ b1,
                                                      const unsigned short* __restrict__ W2t,
                                                      unsigned short* __restrict__ h2b,
                                                      int M) {
    __shared__ unsigned short a4[4][256];  // block's 4 activated rows (bf16)
    int w = threadIdx.x >> 6, lane = threadIdx.x & 63;
    int r = blockIdx.x * 4 + w;
    bool valid = r < M;
    int start = 0, end = 0;
    float dr = 0.f;
    if (valid) {
        start = r ? rp[r - 1] : 0;
        end = rp[r];
        dr = dinv[r];
    }

    const ushort4* hv = (const ushort4*)h1;  // node stride 64 ushort4
    float ax = 0.f, ay = 0.f, az = 0.f, aw = 0.f;
    if (valid) {
        ushort4 v = hv[(size_t)r * 64 + lane];  // self term (dinv[r]-prescaled)
        ax = b2f(v.x); ay = b2f(v.y); az = b2f(v.z); aw = b2f(v.w);
    }

    int e = start;
    for (; e + 8 <= end; e += 8) {
        int s0 = col[e]     & PKMASK, s1 = col[e + 1] & PKMASK;
        int s2 = col[e + 2] & PKMASK, s3 = col[e + 3] & PKMASK;
        int s4 = col[e + 4] & PKMASK, s5 = col[e + 5] & PKMASK;
        int s6 = col[e + 6] & PKMASK, s7 = col[e + 7] & PKMASK;
        ushort4 q0 = hv[(size_t)s0 * 64 + lane];
        ushort4 q1 = hv[(size_t)s1 * 64 + lane];
        ushort4 q2 = hv[(size_t)s2 * 64 + lane];
        ushort4 q3 = hv[(size_t)s3 * 64 + lane];
        ushort4 q4 = hv[(size_t)s4 * 64 + lane];
        ushort4 q5 = hv[(size_t)s5 * 64 + lane];
        ushort4 q6 = hv[(size_t)s6 * 64 + lane];
        ushort4 q7 = hv[(size_t)s7 * 64 + lane];
        ax += ((b2f(q0.x) + b2f(q1.x)) + (b2f(q2.x) + b2f(q3.x)))
            + ((b2f(q4.x) + b2f(q5.x)) + (b2f(q6.x) + b2f(q7.x)));
        ay += ((b2f(q0.y) + b2f(q1.y)) + (b2f(q2.y) + b2f(q3.y)))
            + ((b2f(q4.y) + b2f(q5.y)) + (b2f(q6.y) + b2f(q7.y)));
        az += ((b2f(q0.z) + b2f(q1.z)) + (b2f(q2.z) + b2f(q3.z)))
            + ((b2f(q4.z) + b2f(q5.z)) + (b2f(q6.z) + b2f(q7.z)));
        aw += ((b2f(q0.w) + b2f(q1.w)) + (b2f(q2.w) + b2f(q3.w)))
            + ((b2f(q4.w) + b2f(q5.w)) + (b2f(q6.w) + b2f(q7.w)));
    }
    for (; e < end; e++) {
        ushort4 q = hv[(size_t)(col[e] & PKMASK) * 64 + lane];
        ax += b2f(q.x); ay += b2f(q.y); az += b2f(q.z); aw += b2f(q.w);
    }
    if (valid) {
        float4 bb = *(const float4*)&b1[lane * 4];
        ushort4 o;
        o.x = f2b(fmaxf(dr * ax + bb.x, 0.f));
        o.y = f2b(fmaxf(dr * ay + bb.y, 0.f));
        o.z = f2b(fmaxf(dr * az + bb.z, 0.f));
        o.w = f2b(fmaxf(dr * aw + bb.w, 0.f));
        *(ushort4*)&a4[w][lane * 4] = o;
    }
    __syncthreads();
    // ---- wave 0: project the block's 4 rows with MFMA (rows 4-15 duplicate) --
    if (w == 0) {
        int quad = lane >> 4, l15 = lane & 15;
        int rr4 = l15 & 3;  // clamp A row to 0..3; dup rows' outputs discarded
        f32x4 acc[3] = {};
#pragma unroll
        for (int kt = 0; kt < F_HID; kt += 32) {
            bf16x8 af = *(const bf16x8*)&a4[rr4][kt + quad * 8];
#pragma unroll
            for (int j = 0; j < 3; j++) {
                bf16x8 bf = *(const bf16x8*)&W2t[(size_t)(j * 16 + l15) * F_HID + kt + quad * 8];
                acc[j] = __builtin_amdgcn_mfma_f32_16x16x32_bf16(af, bf, acc[j], 0, 0, 0);
            }
        }
        // D layout: col=l15+j*16, row=quad*4+rr -> valid block rows live in quad 0
        if (quad == 0) {
#pragma unroll
            for (int rr = 0; rr < 4; rr++) {
                int gr = blockIdx.x * 4 + rr;
                if (gr < M) {
                    float dv = dinv[gr];
#pragma unroll
                    for (int j = 0; j < 3; j++) {
                        int c = j * 16 + l15;  // 0..47; cols 41..47 are zeros
                        h2b[(size_t)gr * 64 + c] = f2b(dv * acc[j][rr]);
                    }
                }
            }
        }
    }
}

// ===== CSR aggregation layer 2 (F=41 bf16, dinv-prescaled) + b2 + log_softmax ===
// 4 edges per wave: group g = lanes 16g..16g+15 handles edge e+g; lanes l15<11
// load ushort4 (8 B/lane). Cross-group combine is 2 shuffles per accumulator.

__global__ __launch_bounds__(256) void csr_agg2_lsm(const int* __restrict__ rp,
                                                    const int* __restrict__ col,
                                                    const float* __restrict__ dinv,
                                                    const unsigned short* __restrict__ h2b,
                                                    const float* __restrict__ b2,
                                                    float* __restrict__ out, int M) {
    int w = threadIdx.x >> 6, lane = threadIdx.x & 63;
    int r = blockIdx.x * 4 + w;
    if (r >= M) return;
    int start = r ? rp[r - 1] : 0;
    int end = rp[r];
    float dr = dinv[r];
    int g = lane >> 4, l15 = lane & 15;
    bool act = l15 < 11;  // 11 lanes x 4 classes = 44 >= 41 (+3 zero pads)

    const ushort4* hq = (const ushort4*)h2b;  // row stride 16 ushort4
    float a0 = 0.f, a1 = 0.f, a2 = 0.f, a3 = 0.f;
    if (g == 0 && act) {  // self term (prescaled)
        ushort4 q = hq[(size_t)r * 16 + l15];
        a0 = b2f(q.x); a1 = b2f(q.y); a2 = b2f(q.z); a3 = b2f(q.w);
    }
    int e = start;
    for (; e + 8 <= end; e += 8) {
        int sA = col[e + g] & PKMASK;
        int sB = col[e + 4 + g] & PKMASK;
        if (act) {
            ushort4 qA = hq[(size_t)sA * 16 + l15];
            ushort4 qB = hq[(size_t)sB * 16 + l15];
            a0 += b2f(qA.x) + b2f(qB.x);
            a1 += b2f(qA.y) + b2f(qB.y);
            a2 += b2f(qA.z) + b2f(qB.z);
            a3 += b2f(qA.w) + b2f(qB.w);
        }
    }
    if (e + g < end && act) {
        ushort4 q = hq[(size_t)(col[e + g] & PKMASK) * 16 + l15];
        a0 += b2f(q.x); a1 += b2f(q.y); a2 += b2f(q.z); a3 += b2f(q.w);
    }
    if (e + 4 + g < end && act) {
        ushort4 q = hq[(size_t)(col[e + 4 + g] & PKMASK) * 16 + l15];
        a0 += b2f(q.x); a1 += b2f(q.y); a2 += b2f(q.z); a3 += b2f(q.w);
    }
    // combine the 4 groups (lanes l, l^16, l^32, l^48)
    a0 += __shfl_xor(a0, 16); a0 += __shfl_xor(a0, 32);
    a1 += __shfl_xor(a1, 16); a1 += __shfl_xor(a1, 32);
    a2 += __shfl_xor(a2, 16); a2 += __shfl_xor(a2, 32);
    a3 += __shfl_xor(a3, 16); a3 += __shfl_xor(a3, 32);

    int c0 = l15 * 4;
    float4 bb = make_float4(b2[c0 < N_CLS ? c0 : N_CLS - 1],
                            b2[(c0 + 1 < N_CLS) ? c0 + 1 : N_CLS - 1],
                            b2[(c0 + 2 < N_CLS) ? c0 + 2 : N_CLS - 1],
                            b2[(c0 + 3 < N_CLS) ? c0 + 3 : N_CLS - 1]);
    float v0 = (c0     < N_CLS) ? dr * a0 + bb.x : -INFINITY;
    float v1 = (c0 + 1 < N_CLS) ? dr * a1 + bb.y : -INFINITY;
    float v2 = (c0 + 2 < N_CLS) ? dr * a2 + bb.z : -INFINITY;
    float v3 = (c0 + 3 < N_CLS) ? dr * a3 + bb.w : -INFINITY;

    float m = fmaxf(fmaxf(v0, v1), fmaxf(v2, v3));
#pragma unroll
    for (int off = 1; off < 16; off <<= 1) m = fmaxf(m, __shfl_xor(m, off));
    float s = expf(v0 - m) + expf(v1 - m) + expf(v2 - m) + expf(v3 - m);
#pragma unroll
    for (int off = 1; off < 16; off <<= 1) s += __shfl_xor(s, off);
    float ls = m + logf(s);

    if (g == 0) {
        float* orow = &out[(size_t)r * N_CLS];
        if (c0 < N_CLS)     __builtin_nontemporal_store(v0 - ls, &orow[c0]);
        if (c0 + 1 < N_CLS) __builtin_nontemporal_store(v1 - ls, &orow[c0 + 1]);
        if (c0 + 2 < N_CLS) __builtin_nontemporal_store(v2 - ls, &orow[c0 + 2]);
        if (c0 + 3 < N_CLS) __builtin_nontemporal_store(v3 - ls, &orow[c0 + 3]);
    }
}

// ================= launch =================

extern "C" void kernel_launch(void* const* d_in, const int* in_sizes, int n_in,
                              void* d_out, int out_size, void* d_ws, size_t ws_size,
                              hipStream_t stream) {
    const float* x  = (const float*)d_in[0];
    const int*   ei = (const int*)d_in[1];
    const float* W1 = (const float*)d_in[2];
    const float* b1 = (const float*)d_in[3];
    const float* W2 = (const float*)d_in[4];
    const float* b2 = (const float*)d_in[5];
    float* out = (float*)d_out;

    const int M = in_sizes[0] / F_IN;       // 100000
    const int E = in_sizes[1] / 2;          // 3200000
    const int* esrc = ei;
    const int* edst = ei + E;

    const int NBK = (M + 31) / 32;          // 3125 buckets of 32 dst nodes
    const int NW  = (E + CHUNK - 1) / CHUNK; // 196 edge chunks

    // workspace layout (bytes, 128-aligned)
    char* ws = (char*)d_ws;
    float*          dinv    = (float*)(ws);                         //     400,128
    int*            rp      = (int*)  (ws +    400128);             //     400,128
    int*            bbase   = (int*)  (ws +    800256);             //      12,544
    int*            btot    = (int*)  (ws +    812800);             //      12,544
    int*            hist_g  = (int*)  (ws +    825344);             //   2,450,048
    int*            packed  = (int*)  (ws +   3275392ull);          //  12,800,000
    int*            packed2 = (int*)  (ws +  16075392ull);          //  12,800,000
    unsigned short* W1t     = (unsigned short*)(ws + 28875392ull);  //     262,144
    unsigned short* W2t     = (unsigned short*)(ws + 29137536ull);  //      24,576
    unsigned short* h1      = (unsigned short*)(ws + 29162112ull);  //  51,200,000
    unsigned short* h2b     = (unsigned short*)(ws + 80362112ull);  //  12,800,000

    // --- CSR build (bucketed, no global atomic storms) ---
    hist_pass<<<NW, 256, 0, stream>>>(edst, hist_g, E, NBK, NW);
    s1_btot<<<(NBK + 255) / 256, 256, 0, stream>>>(hist_g, btot, NBK, NW);
    s2_scan<<<1, 256, 0, stream>>>(btot, bbase, NBK);
    s3_rowscan<<<(NBK + 255) / 256, 256, 0, stream>>>(hist_g, bbase, NBK, NW);
    scatter_pass<<<NW, 256, 0, stream>>>(esrc, edst, hist_g, packed, E, NBK, NW);
    bucket_sort<<<NBK, 256, 0, stream>>>(packed, bbase, packed2, rp, dinv, M);

    // --- weight prep ---
    cvt_W1t<<<32, 256, 0, stream>>>(W1, W1t);
    cvt_W2t<<<48, 256, 0, stream>>>(W2, W2t);

    // --- layer 1 (+ fused layer-2 linear) ---
    mfma_gemm1<<<(M + 127) / 128, 512, 0, stream>>>(x, W1t, dinv, h1, M);
    csr_agg1_fused<<<(M + 3) / 4, 256, 0, stream>>>(rp, packed2, dinv, h1, b1,
                                                    W2t, h2b, M);

    // --- layer 2 aggregation + log_softmax ---
    csr_agg2_lsm<<<(M + 3) / 4, 256, 0, stream>>>(rp, packed2, dinv, h2b, b2, out, M);
}